// Round 4
// baseline (363.317 us; speedup 1.0000x reference)
//
#include <hip/hip_runtime.h>

#define N_NODES 4096
#define N_EDGES 131072
#define BATCH   16
#define HDIM    16
#define FCDIM   20
#define BH      256              // BATCH*HDIM
#define ISD     0.17677669529663687f  // 1/sqrt(E/N) = 1/sqrt(32)

// ---------------- setup: ew, G[b][j][k], invF, zero d_out + cnt -------------
__global__ void setup_kernel(const float* __restrict__ F, const float* __restrict__ W_in,
                             const float* __restrict__ fc1_0, const float* __restrict__ fc2_0,
                             const float* __restrict__ fc1_1, const float* __restrict__ fc2_1,
                             float* __restrict__ ew, float* __restrict__ G,
                             float* __restrict__ invF, float* __restrict__ out144,
                             int* __restrict__ cnt) {
    int t = threadIdx.x;
    if (t < 6) {
        const float* fc1 = (t < 3) ? fc1_0 : fc1_1;
        const float* fc2 = (t < 3) ? fc2_0 : fc2_1;
        int ty = t % 3;
        float s = 0.f;
        for (int f = 0; f < FCDIM; ++f) {
            float v = fc1[ty * FCDIM + f];
            v = v > 0.f ? v : 0.f;
            s += v * fc2[f];
        }
        ew[t] = s;
    }
    for (int idx = t; idx < BATCH * 3 * HDIM; idx += 256) {
        int b = idx / 48, r = idx % 48, j = r / HDIM, k = r % HDIM;
        float s = 0.f;
        for (int i = 0; i < 3; ++i) s += F[b * 9 + i * 3 + j] * W_in[i * HDIM + k];
        G[idx] = s;
    }
    if (t < BATCH) {
        const float* f = F + t * 9;
        float a00=f[0],a01=f[1],a02=f[2],a10=f[3],a11=f[4],a12=f[5],a20=f[6],a21=f[7],a22=f[8];
        float det = a00*(a11*a22-a12*a21) - a01*(a10*a22-a12*a20) + a02*(a10*a21-a11*a20);
        float id = 1.f/det;
        float* o = invF + t*9;
        o[0]=(a11*a22-a12*a21)*id; o[1]=(a02*a21-a01*a22)*id; o[2]=(a01*a12-a02*a11)*id;
        o[3]=(a12*a20-a10*a22)*id; o[4]=(a00*a22-a02*a20)*id; o[5]=(a02*a10-a00*a12)*id;
        o[6]=(a10*a21-a11*a20)*id; o[7]=(a01*a20-a00*a21)*id; o[8]=(a00*a11-a01*a10)*id;
    }
    if (t < 144) out144[t] = 0.f;
    for (int i = t; i < N_NODES; i += 256) cnt[i] = 0;
}

// ---------------- h0[n][b*16+k] = sum_j pos[n][j]*G[b][j][k]; zero tmat -----
__global__ void h0_kernel(const float* __restrict__ pos, const float* __restrict__ G,
                          float* __restrict__ h0, float* __restrict__ tmat) {
    int id = blockIdx.x * 256 + threadIdx.x;   // 0..262143
    if (id < N_NODES * 48) tmat[id] = 0.f;
    int n  = id >> 6;
    int c4 = (id & 63) << 2;
    int b  = c4 >> 4;
    int k  = c4 & 15;
    float p0 = pos[n*3+0], p1 = pos[n*3+1], p2 = pos[n*3+2];
    const float* g = G + b*48 + k;
    float4 r;
    r.x = p0*g[0] + p1*g[16] + p2*g[32];
    r.y = p0*g[1] + p1*g[17] + p2*g[33];
    r.z = p0*g[2] + p1*g[18] + p2*g[34];
    r.w = p0*g[3] + p1*g[19] + p2*g[35];
    *(float4*)(h0 + n*BH + c4) = r;
}

// ---------------- CSR build -------------------------------------------------
__global__ void hist_kernel(const int* __restrict__ dst, int* __restrict__ cnt) {
    int e = blockIdx.x * 256 + threadIdx.x;
    if (e < N_EDGES) atomicAdd(&cnt[dst[e]], 1);
}
__global__ void scan_kernel(const int* __restrict__ cnt, int* __restrict__ off,
                            int* __restrict__ cursor) {
    __shared__ int part[256];
    __shared__ int pref[257];
    int t = threadIdx.x;
    int base = t * 16;
    int loc[16];
    int s = 0;
    #pragma unroll
    for (int i = 0; i < 16; ++i) { loc[i] = s; s += cnt[base + i]; }
    part[t] = s;
    __syncthreads();
    if (t == 0) {
        int acc = 0;
        for (int i = 0; i < 256; ++i) { pref[i] = acc; acc += part[i]; }
        pref[256] = acc;
    }
    __syncthreads();
    int p = pref[t];
    #pragma unroll
    for (int i = 0; i < 16; ++i) {
        int v = p + loc[i];
        off[base + i] = v;
        cursor[base + i] = v;
    }
    if (t == 0) off[N_NODES] = pref[256];
}
__global__ void fill_kernel(const int* __restrict__ src, const int* __restrict__ dst,
                            const int* __restrict__ typ, int* __restrict__ cursor,
                            int* __restrict__ sedge) {
    int e = blockIdx.x * 256 + threadIdx.x;
    if (e < N_EDGES) {
        int p = atomicAdd(&cursor[dst[e]], 1);
        sedge[p] = src[e] | (typ[e] << 16);
    }
}

// ---------------- one GCN layer: gather+scale, @W, relu ---------------------
// 2 waves per dst node (half-row each, float2 lanes); grid 2048 -> 32 waves/CU
__global__ void layer_kernel(const float* __restrict__ h_in, float* __restrict__ h_out,
                             const int* __restrict__ off, const int* __restrict__ sedge,
                             const float* __restrict__ ew3, const float* __restrict__ W) {
    __shared__ float Wl[256];
    __shared__ float aggS[2][16*17 + 4];
    int t = threadIdx.x;
    Wl[t] = W[t];
    int wave = t >> 6, lane = t & 63;
    int node = wave >> 1;
    int half = wave & 1;
    int d = blockIdx.x * 2 + node;
    float e0 = ew3[0], e1 = ew3[1], e2 = ew3[2];
    int beg = off[d], end = off[d+1];
    int col = half * 128 + lane * 2;
    float2 acc = {0.f, 0.f};
    int it = beg;
    for (; it + 7 < end; it += 8) {
        int v[8]; float2 hv[8];
        #pragma unroll
        for (int u = 0; u < 8; ++u) v[u] = sedge[it + u];
        #pragma unroll
        for (int u = 0; u < 8; ++u)
            hv[u] = *(const float2*)(h_in + (v[u] & 0xFFFF) * BH + col);
        #pragma unroll
        for (int u = 0; u < 8; ++u) {
            int ty = v[u] >> 16;
            float wg = (ty == 0) ? e0 : (ty == 1 ? e1 : e2);
            acc.x += wg * hv[u].x; acc.y += wg * hv[u].y;
        }
    }
    for (; it < end; ++it) {
        int v = sedge[it];
        int ty = v >> 16;
        float wg = (ty == 0) ? e0 : (ty == 1 ? e1 : e2);
        float2 hv = *(const float2*)(h_in + (v & 0xFFFF) * BH + col);
        acc.x += wg * hv.x; acc.y += wg * hv.y;
    }
    int b = col >> 4, k0 = col & 15;
    aggS[node][b*17 + k0]     = acc.x * ISD;
    aggS[node][b*17 + k0 + 1] = acc.y * ISD;
    __syncthreads();
    // epilogue: thread t -> node t>>7, 2 cols (t&127)*2
    int en = t >> 7, c2 = (t & 127) * 2;
    int eb = c2 >> 4, ek = c2 & 15;
    const float* arow = aggS[en] + eb * 17;
    float o0 = 0.f, o1 = 0.f;
    #pragma unroll
    for (int k = 0; k < 16; ++k) {
        float av = arow[k];
        o0 += av * Wl[k*16 + ek];
        o1 += av * Wl[k*16 + ek + 1];
    }
    int ed = blockIdx.x * 2 + en;
    float2 r;
    r.x = o0 > 0.f ? o0 : 0.f;
    r.y = o1 > 0.f ? o1 : 0.f;
    *(float2*)(h_out + ed*BH + c2) = r;
}

// ---------------- hout[n][b*3+p] = sum_k h2[n][b*16+k] * W_out[k][p] --------
__global__ void hout_kernel(const float* __restrict__ h2, const float* __restrict__ Wout,
                            float* __restrict__ hout) {
    __shared__ float Wo[48];
    int t = threadIdx.x;
    if (t < 48) Wo[t] = Wout[t];
    __syncthreads();
    int id = blockIdx.x * 256 + t;
    int n = id >> 4, b = id & 15;
    const float* hr = h2 + n*BH + b*HDIM;
    float s0=0.f, s1=0.f, s2=0.f;
    #pragma unroll
    for (int k = 0; k < 16; ++k) {
        float v = hr[k];
        s0 += v*Wo[k*3+0]; s1 += v*Wo[k*3+1]; s2 += v*Wo[k*3+2];
    }
    float* o = hout + n*48 + b*3;
    o[0]=s0; o[1]=s1; o[2]=s2;
}

// ---------------- a, c for first N edges ------------------------------------
__global__ void ac_kernel(const float* __restrict__ hout, const int* __restrict__ esrc,
                          const int* __restrict__ edst, const float* __restrict__ invF,
                          float* __restrict__ a, float* __restrict__ c) {
    __shared__ float iF[144];
    int t = threadIdx.x;
    if (t < 144) iF[t] = invF[t];
    __syncthreads();
    int id = blockIdx.x * 256 + t;
    int i = id >> 4, b = id & 15;
    int s = esrc[i], d = edst[i];
    float a0 = hout[s*48+b*3+0] - hout[d*48+b*3+0];
    float a1 = hout[s*48+b*3+1] - hout[d*48+b*3+1];
    float a2 = hout[s*48+b*3+2] - hout[d*48+b*3+2];
    float* ap = a + i*48 + b*3;
    ap[0]=a0; ap[1]=a1; ap[2]=a2;
    const float* m = iF + b*9;
    float* cp = c + i*48 + b*3;
    cp[0] = m[0]*a0 + m[1]*a1 + m[2]*a2;
    cp[1] = m[3]*a0 + m[4]*a1 + m[5]*a2;
    cp[2] = m[6]*a0 + m[7]*a1 + m[8]*a2;
}

// ---------------- stage 1: t[j][col] = sum_i W2[i][j] * a[i][col] -----------
// grid 1024 = 64 jb-tiles x 16 i-strips(256). Thread: j = jb+lane (coalesced
// W2 row reads, shared by 4 waves via L1), colgroup = wave*12 (readfirstlane
// -> a reads scalarize to s_load). 3 float4 accums/thread: no spill.
__global__ __launch_bounds__(256)
void tmat_kernel(const float* __restrict__ W2, const float* __restrict__ a,
                 float* __restrict__ tmat) {
    int t = threadIdx.x;
    int lane = t & 63;
    int cg = __builtin_amdgcn_readfirstlane((t >> 6) * 12);
    int jb = (blockIdx.x & 63) * 64;
    int i0 = (blockIdx.x >> 6) * 256;
    int j  = jb + lane;
    const float* w2p = W2 + j;
    const float* ap  = a + cg;
    float4 A0 = {0,0,0,0}, A1 = {0,0,0,0}, A2 = {0,0,0,0};
    for (int i = i0; i < i0 + 256; i += 4) {
        float w0 = w2p[(size_t)(i+0) * N_NODES];
        float w1 = w2p[(size_t)(i+1) * N_NODES];
        float w2v = w2p[(size_t)(i+2) * N_NODES];
        float w3 = w2p[(size_t)(i+3) * N_NODES];
        #pragma unroll
        for (int u = 0; u < 4; ++u) {
            float wv = (u == 0) ? w0 : (u == 1) ? w1 : (u == 2) ? w2v : w3;
            const float* ar = ap + (size_t)(i + u) * 48;
            float4 x = *(const float4*)(ar);
            float4 y = *(const float4*)(ar + 4);
            float4 z = *(const float4*)(ar + 8);
            A0.x += wv*x.x; A0.y += wv*x.y; A0.z += wv*x.z; A0.w += wv*x.w;
            A1.x += wv*y.x; A1.y += wv*y.y; A1.z += wv*y.z; A1.w += wv*y.w;
            A2.x += wv*z.x; A2.y += wv*z.y; A2.z += wv*z.z; A2.w += wv*z.w;
        }
    }
    float* tp = tmat + (size_t)j * 48 + cg;
    atomicAdd(tp + 0,  A0.x); atomicAdd(tp + 1,  A0.y);
    atomicAdd(tp + 2,  A0.z); atomicAdd(tp + 3,  A0.w);
    atomicAdd(tp + 4,  A1.x); atomicAdd(tp + 5,  A1.y);
    atomicAdd(tp + 6,  A1.z); atomicAdd(tp + 7,  A1.w);
    atomicAdd(tp + 8,  A2.x); atomicAdd(tp + 9,  A2.y);
    atomicAdd(tp + 10, A2.z); atomicAdd(tp + 11, A2.w);
}

// ---------------- stage 2: stress[b,p,q] = sum_j t[j,bp] * c[j,bq] ----------
// grid 64: block owns 64 j; thread = (jl = t>>4, b = t&15), 4 passes of j.
__global__ void stress2_kernel(const float* __restrict__ tmat, const float* __restrict__ c,
                               float* __restrict__ out) {
    __shared__ float shred[256 * 9];
    int t = threadIdx.x;
    int b = t & 15, jl = t >> 4;
    int jbase = blockIdx.x * 64;
    float s[9];
    #pragma unroll
    for (int r = 0; r < 9; ++r) s[r] = 0.f;
    for (int pass = 0; pass < 4; ++pass) {
        int j = jbase + pass * 16 + jl;
        const float* tp = tmat + (size_t)j * 48 + b * 3;
        const float* cp = c + (size_t)j * 48 + b * 3;
        float t0 = tp[0], t1 = tp[1], t2 = tp[2];
        float c0 = cp[0], c1 = cp[1], c2 = cp[2];
        s[0] += t0*c0; s[1] += t0*c1; s[2] += t0*c2;
        s[3] += t1*c0; s[4] += t1*c1; s[5] += t1*c2;
        s[6] += t2*c0; s[7] += t2*c1; s[8] += t2*c2;
    }
    #pragma unroll
    for (int r = 0; r < 9; ++r) shred[t * 9 + r] = s[r];
    __syncthreads();
    if (t < 144) {
        int bb = t / 9, r = t % 9;
        float acc = 0.f;
        #pragma unroll
        for (int g = 0; g < 16; ++g)
            acc += shred[(g * 16 + bb) * 9 + r];
        atomicAdd(&out[t], acc);
    }
}

extern "C" void kernel_launch(void* const* d_in, const int* in_sizes, int n_in,
                              void* d_out, int out_size, void* d_ws, size_t ws_size,
                              hipStream_t stream) {
    const float* F     = (const float*)d_in[0];
    const float* pos   = (const float*)d_in[1];
    const int*   esrc  = (const int*)d_in[2];
    const int*   edst  = (const int*)d_in[3];
    const int*   etyp  = (const int*)d_in[4];
    const float* W_in  = (const float*)d_in[5];
    const float* fc1_0 = (const float*)d_in[6];
    const float* fc2_0 = (const float*)d_in[7];
    const float* W_0   = (const float*)d_in[8];
    const float* fc1_1 = (const float*)d_in[9];
    const float* fc2_1 = (const float*)d_in[10];
    const float* W_1   = (const float*)d_in[11];
    const float* W_out = (const float*)d_in[12];
    const float* w2    = (const float*)d_in[13];
    float* out = (float*)d_out;

    float* ws   = (float*)d_ws;
    float* ew   = ws;                     // 6
    float* G    = ws + 16;                // 768
    float* invF = ws + 800;               // 144
    float* bufA = ws + 1024;              // N*256
    float* bufB = bufA + N_NODES*BH;      // N*256
    float* hout = bufB + N_NODES*BH;      // N*48
    float* aArr = hout + N_NODES*48;      // N*48
    float* cArr = aArr + N_NODES*48;      // N*48
    float* tmat = cArr + N_NODES*48;      // N*48
    int* cnt    = (int*)(tmat + N_NODES*48);
    int* off    = cnt + N_NODES;          // N+1
    int* cursor = off + N_NODES + 1;      // N
    int* sedge  = cursor + N_NODES;       // E

    setup_kernel<<<1, 256, 0, stream>>>(F, W_in, fc1_0, fc2_0, fc1_1, fc2_1, ew, G, invF, out, cnt);
    h0_kernel<<<1024, 256, 0, stream>>>(pos, G, bufA, tmat);
    hist_kernel<<<512, 256, 0, stream>>>(edst, cnt);
    scan_kernel<<<1, 256, 0, stream>>>(cnt, off, cursor);
    fill_kernel<<<512, 256, 0, stream>>>(esrc, edst, etyp, cursor, sedge);
    layer_kernel<<<2048, 256, 0, stream>>>(bufA, bufB, off, sedge, ew,     W_0);
    layer_kernel<<<2048, 256, 0, stream>>>(bufB, bufA, off, sedge, ew + 3, W_1);
    hout_kernel<<<256, 256, 0, stream>>>(bufA, W_out, hout);
    ac_kernel<<<256, 256, 0, stream>>>(hout, esrc, edst, invF, aArr, cArr);
    tmat_kernel<<<1024, 256, 0, stream>>>(w2, aArr, tmat);
    stress2_kernel<<<64, 256, 0, stream>>>(tmat, cArr, out);
}

// Round 5
// 257.394 us; speedup vs baseline: 1.4115x; 1.4115x over previous
//
#include <hip/hip_runtime.h>

#define N_NODES 4096
#define N_EDGES 131072
#define BATCH   16
#define HDIM    16
#define FCDIM   20
#define BH      256              // BATCH*HDIM
#define ISD     0.17677669529663687f  // 1/sqrt(E/N) = 1/sqrt(32)
#define NSTRIP  32               // tmat i-strips

// ---------------- setup: ew, G[b][j][k], invF, zero d_out + cnt -------------
__global__ void setup_kernel(const float* __restrict__ F, const float* __restrict__ W_in,
                             const float* __restrict__ fc1_0, const float* __restrict__ fc2_0,
                             const float* __restrict__ fc1_1, const float* __restrict__ fc2_1,
                             float* __restrict__ ew, float* __restrict__ G,
                             float* __restrict__ invF, float* __restrict__ out144,
                             int* __restrict__ cnt) {
    int t = threadIdx.x;
    if (t < 6) {
        const float* fc1 = (t < 3) ? fc1_0 : fc1_1;
        const float* fc2 = (t < 3) ? fc2_0 : fc2_1;
        int ty = t % 3;
        float s = 0.f;
        for (int f = 0; f < FCDIM; ++f) {
            float v = fc1[ty * FCDIM + f];
            v = v > 0.f ? v : 0.f;
            s += v * fc2[f];
        }
        ew[t] = s;
    }
    for (int idx = t; idx < BATCH * 3 * HDIM; idx += 256) {
        int b = idx / 48, r = idx % 48, j = r / HDIM, k = r % HDIM;
        float s = 0.f;
        for (int i = 0; i < 3; ++i) s += F[b * 9 + i * 3 + j] * W_in[i * HDIM + k];
        G[idx] = s;
    }
    if (t < BATCH) {
        const float* f = F + t * 9;
        float a00=f[0],a01=f[1],a02=f[2],a10=f[3],a11=f[4],a12=f[5],a20=f[6],a21=f[7],a22=f[8];
        float det = a00*(a11*a22-a12*a21) - a01*(a10*a22-a12*a20) + a02*(a10*a21-a11*a20);
        float id = 1.f/det;
        float* o = invF + t*9;
        o[0]=(a11*a22-a12*a21)*id; o[1]=(a02*a21-a01*a22)*id; o[2]=(a01*a12-a02*a11)*id;
        o[3]=(a12*a20-a10*a22)*id; o[4]=(a00*a22-a02*a20)*id; o[5]=(a02*a10-a00*a12)*id;
        o[6]=(a10*a21-a11*a20)*id; o[7]=(a01*a20-a00*a21)*id; o[8]=(a00*a11-a01*a10)*id;
    }
    if (t < 144) out144[t] = 0.f;
    for (int i = t; i < N_NODES; i += 256) cnt[i] = 0;
}

// ---------------- fused: h0 compute (blocks 0..1023) + edge hist (1024..1535)
__global__ void h0_hist_kernel(const float* __restrict__ pos, const float* __restrict__ G,
                               float* __restrict__ h0,
                               const int* __restrict__ edst, int* __restrict__ cnt) {
    int bid = blockIdx.x;
    int t = threadIdx.x;
    if (bid < 1024) {
        int id = bid * 256 + t;
        int n  = id >> 6;
        int c4 = (id & 63) << 2;
        int b  = c4 >> 4;
        int k  = c4 & 15;
        float p0 = pos[n*3+0], p1 = pos[n*3+1], p2 = pos[n*3+2];
        const float* g = G + b*48 + k;
        float4 r;
        r.x = p0*g[0] + p1*g[16] + p2*g[32];
        r.y = p0*g[1] + p1*g[17] + p2*g[33];
        r.z = p0*g[2] + p1*g[18] + p2*g[34];
        r.w = p0*g[3] + p1*g[19] + p2*g[35];
        *(float4*)(h0 + n*BH + c4) = r;
    } else {
        int e = (bid - 1024) * 256 + t;
        if (e < N_EDGES) atomicAdd(&cnt[edst[e]], 1);
    }
}

// ---------------- CSR build -------------------------------------------------
__global__ void scan_kernel(const int* __restrict__ cnt, int* __restrict__ off,
                            int* __restrict__ cursor) {
    __shared__ int part[256];
    __shared__ int pref[257];
    int t = threadIdx.x;
    int base = t * 16;
    int loc[16];
    int s = 0;
    #pragma unroll
    for (int i = 0; i < 16; ++i) { loc[i] = s; s += cnt[base + i]; }
    part[t] = s;
    __syncthreads();
    if (t == 0) {
        int acc = 0;
        for (int i = 0; i < 256; ++i) { pref[i] = acc; acc += part[i]; }
        pref[256] = acc;
    }
    __syncthreads();
    int p = pref[t];
    #pragma unroll
    for (int i = 0; i < 16; ++i) {
        int v = p + loc[i];
        off[base + i] = v;
        cursor[base + i] = v;
    }
    if (t == 0) off[N_NODES] = pref[256];
}
__global__ void fill_kernel(const int* __restrict__ src, const int* __restrict__ dst,
                            const int* __restrict__ typ, int* __restrict__ cursor,
                            int* __restrict__ sedge) {
    int e = blockIdx.x * 256 + threadIdx.x;
    if (e < N_EDGES) {
        int p = atomicAdd(&cursor[dst[e]], 1);
        sedge[p] = src[e] | (typ[e] << 16);
    }
}

// ---------------- one GCN layer: gather+scale, @W, relu ---------------------
// 2 waves per dst node (half-row each, float2 lanes); grid 2048 -> 32 waves/CU
__global__ void layer_kernel(const float* __restrict__ h_in, float* __restrict__ h_out,
                             const int* __restrict__ off, const int* __restrict__ sedge,
                             const float* __restrict__ ew3, const float* __restrict__ W) {
    __shared__ float Wl[256];
    __shared__ float aggS[2][16*17 + 4];
    int t = threadIdx.x;
    Wl[t] = W[t];
    int wave = t >> 6, lane = t & 63;
    int node = wave >> 1;
    int half = wave & 1;
    int d = blockIdx.x * 2 + node;
    float e0 = ew3[0], e1 = ew3[1], e2 = ew3[2];
    int beg = off[d], end = off[d+1];
    int col = half * 128 + lane * 2;
    float2 acc = {0.f, 0.f};
    int it = beg;
    for (; it + 7 < end; it += 8) {
        int v[8]; float2 hv[8];
        #pragma unroll
        for (int u = 0; u < 8; ++u) v[u] = sedge[it + u];
        #pragma unroll
        for (int u = 0; u < 8; ++u)
            hv[u] = *(const float2*)(h_in + (v[u] & 0xFFFF) * BH + col);
        #pragma unroll
        for (int u = 0; u < 8; ++u) {
            int ty = v[u] >> 16;
            float wg = (ty == 0) ? e0 : (ty == 1 ? e1 : e2);
            acc.x += wg * hv[u].x; acc.y += wg * hv[u].y;
        }
    }
    for (; it < end; ++it) {
        int v = sedge[it];
        int ty = v >> 16;
        float wg = (ty == 0) ? e0 : (ty == 1 ? e1 : e2);
        float2 hv = *(const float2*)(h_in + (v & 0xFFFF) * BH + col);
        acc.x += wg * hv.x; acc.y += wg * hv.y;
    }
    int b = col >> 4, k0 = col & 15;
    aggS[node][b*17 + k0]     = acc.x * ISD;
    aggS[node][b*17 + k0 + 1] = acc.y * ISD;
    __syncthreads();
    int en = t >> 7, c2 = (t & 127) * 2;
    int eb = c2 >> 4, ek = c2 & 15;
    const float* arow = aggS[en] + eb * 17;
    float o0 = 0.f, o1 = 0.f;
    #pragma unroll
    for (int k = 0; k < 16; ++k) {
        float av = arow[k];
        o0 += av * Wl[k*16 + ek];
        o1 += av * Wl[k*16 + ek + 1];
    }
    int ed = blockIdx.x * 2 + en;
    float2 r;
    r.x = o0 > 0.f ? o0 : 0.f;
    r.y = o1 > 0.f ? o1 : 0.f;
    *(float2*)(h_out + ed*BH + c2) = r;
}

// ---------------- hout[n][b*3+p] = sum_k h2[n][b*16+k] * W_out[k][p] --------
__global__ void hout_kernel(const float* __restrict__ h2, const float* __restrict__ Wout,
                            float* __restrict__ hout) {
    __shared__ float Wo[48];
    int t = threadIdx.x;
    if (t < 48) Wo[t] = Wout[t];
    __syncthreads();
    int id = blockIdx.x * 256 + t;
    int n = id >> 4, b = id & 15;
    const float* hr = h2 + n*BH + b*HDIM;
    float s0=0.f, s1=0.f, s2=0.f;
    #pragma unroll
    for (int k = 0; k < 16; ++k) {
        float v = hr[k];
        s0 += v*Wo[k*3+0]; s1 += v*Wo[k*3+1]; s2 += v*Wo[k*3+2];
    }
    float* o = hout + n*48 + b*3;
    o[0]=s0; o[1]=s1; o[2]=s2;
}

// ---------------- a, c for first N edges ------------------------------------
__global__ void ac_kernel(const float* __restrict__ hout, const int* __restrict__ esrc,
                          const int* __restrict__ edst, const float* __restrict__ invF,
                          float* __restrict__ a, float* __restrict__ c) {
    __shared__ float iF[144];
    int t = threadIdx.x;
    if (t < 144) iF[t] = invF[t];
    __syncthreads();
    int id = blockIdx.x * 256 + t;
    int i = id >> 4, b = id & 15;
    int s = esrc[i], d = edst[i];
    float a0 = hout[s*48+b*3+0] - hout[d*48+b*3+0];
    float a1 = hout[s*48+b*3+1] - hout[d*48+b*3+1];
    float a2 = hout[s*48+b*3+2] - hout[d*48+b*3+2];
    float* ap = a + i*48 + b*3;
    ap[0]=a0; ap[1]=a1; ap[2]=a2;
    const float* m = iF + b*9;
    float* cp = c + i*48 + b*3;
    cp[0] = m[0]*a0 + m[1]*a1 + m[2]*a2;
    cp[1] = m[3]*a0 + m[4]*a1 + m[5]*a2;
    cp[2] = m[6]*a0 + m[7]*a1 + m[8]*a2;
}

// ---------------- stage 1: partial[s][j][col] = sum_{i in strip s} W2[i][j]*a[i][col]
// grid 512 = 16 j-tiles(256 j) x 32 i-strips(128 i). Thread: 4 consecutive j
// (float4 W2 load, 16B/lane coalesced) x 12 cols (wave's col-group).
// 48 accumulators, ALL statically indexed (no dynamic indexing -> no scratch).
// a-row reads are wave-uniform broadcasts (L1/L2 hit). Plain stores, no atomics.
__global__ __launch_bounds__(256, 4)
void tmat_kernel(const float* __restrict__ W2, const float* __restrict__ a,
                 float* __restrict__ partial) {
    int t = threadIdx.x;
    int lane = t & 63;
    int wave = t >> 6;
    int cg = wave * 12;
    int jb    = (blockIdx.x & 15) * 256;
    int strip = blockIdx.x >> 4;
    int i0    = strip * 128;
    int j     = jb + lane * 4;
    const float* w2p = W2 + (size_t)i0 * N_NODES + j;
    const float* ap  = a + (size_t)i0 * 48 + cg;
    float4 A0x={0,0,0,0},A0y={0,0,0,0},A0z={0,0,0,0};
    float4 A1x={0,0,0,0},A1y={0,0,0,0},A1z={0,0,0,0};
    float4 A2x={0,0,0,0},A2y={0,0,0,0},A2z={0,0,0,0};
    float4 A3x={0,0,0,0},A3y={0,0,0,0},A3z={0,0,0,0};
    for (int ii = 0; ii < 128; ii += 4) {
        float4 w0 = *(const float4*)(w2p + (size_t)(ii+0) * N_NODES);
        float4 w1 = *(const float4*)(w2p + (size_t)(ii+1) * N_NODES);
        float4 w2v = *(const float4*)(w2p + (size_t)(ii+2) * N_NODES);
        float4 w3 = *(const float4*)(w2p + (size_t)(ii+3) * N_NODES);
        #pragma unroll
        for (int u = 0; u < 4; ++u) {
            float4 wv = (u==0)?w0:(u==1)?w1:(u==2)?w2v:w3;
            const float* ar = ap + (size_t)(ii+u) * 48;
            float4 x = *(const float4*)(ar);
            float4 y = *(const float4*)(ar+4);
            float4 z = *(const float4*)(ar+8);
            A0x.x+=wv.x*x.x; A0x.y+=wv.x*x.y; A0x.z+=wv.x*x.z; A0x.w+=wv.x*x.w;
            A0y.x+=wv.x*y.x; A0y.y+=wv.x*y.y; A0y.z+=wv.x*y.z; A0y.w+=wv.x*y.w;
            A0z.x+=wv.x*z.x; A0z.y+=wv.x*z.y; A0z.z+=wv.x*z.z; A0z.w+=wv.x*z.w;
            A1x.x+=wv.y*x.x; A1x.y+=wv.y*x.y; A1x.z+=wv.y*x.z; A1x.w+=wv.y*x.w;
            A1y.x+=wv.y*y.x; A1y.y+=wv.y*y.y; A1y.z+=wv.y*y.z; A1y.w+=wv.y*y.w;
            A1z.x+=wv.y*z.x; A1z.y+=wv.y*z.y; A1z.z+=wv.y*z.z; A1z.w+=wv.y*z.w;
            A2x.x+=wv.z*x.x; A2x.y+=wv.z*x.y; A2x.z+=wv.z*x.z; A2x.w+=wv.z*x.w;
            A2y.x+=wv.z*y.x; A2y.y+=wv.z*y.y; A2y.z+=wv.z*y.z; A2y.w+=wv.z*y.w;
            A2z.x+=wv.z*z.x; A2z.y+=wv.z*z.y; A2z.z+=wv.z*z.z; A2z.w+=wv.z*z.w;
            A3x.x+=wv.w*x.x; A3x.y+=wv.w*x.y; A3x.z+=wv.w*x.z; A3x.w+=wv.w*x.w;
            A3y.x+=wv.w*y.x; A3y.y+=wv.w*y.y; A3y.z+=wv.w*y.z; A3y.w+=wv.w*y.w;
            A3z.x+=wv.w*z.x; A3z.y+=wv.w*z.y; A3z.z+=wv.w*z.z; A3z.w+=wv.w*z.w;
        }
    }
    float* pp = partial + (size_t)strip * (N_NODES*48) + (size_t)j * 48 + cg;
    *(float4*)(pp + 0*48 + 0) = A0x; *(float4*)(pp + 0*48 + 4) = A0y; *(float4*)(pp + 0*48 + 8) = A0z;
    *(float4*)(pp + 1*48 + 0) = A1x; *(float4*)(pp + 1*48 + 4) = A1y; *(float4*)(pp + 1*48 + 8) = A1z;
    *(float4*)(pp + 2*48 + 0) = A2x; *(float4*)(pp + 2*48 + 4) = A2y; *(float4*)(pp + 2*48 + 8) = A2z;
    *(float4*)(pp + 3*48 + 0) = A3x; *(float4*)(pp + 3*48 + 4) = A3y; *(float4*)(pp + 3*48 + 8) = A3z;
}

// ---------------- reduce partials: tmat = sum_s partial[s] ------------------
__global__ void reduce_kernel(const float* __restrict__ partial, float* __restrict__ tmat) {
    int x = (blockIdx.x * 256 + threadIdx.x) * 4;   // 49152 float4s -> 192 blocks
    float4 s = {0.f, 0.f, 0.f, 0.f};
    #pragma unroll 4
    for (int st = 0; st < NSTRIP; ++st) {
        float4 v = *(const float4*)(partial + (size_t)st * (N_NODES*48) + x);
        s.x += v.x; s.y += v.y; s.z += v.z; s.w += v.w;
    }
    *(float4*)(tmat + x) = s;
}

// ---------------- stage 2: stress[b,p,q] = sum_j t[j,bp] * c[j,bq] ----------
__global__ void stress2_kernel(const float* __restrict__ tmat, const float* __restrict__ c,
                               float* __restrict__ out) {
    __shared__ float shred[256 * 9];
    int t = threadIdx.x;
    int b = t & 15, jl = t >> 4;
    int jbase = blockIdx.x * 64;
    float s[9];
    #pragma unroll
    for (int r = 0; r < 9; ++r) s[r] = 0.f;
    for (int pass = 0; pass < 4; ++pass) {
        int j = jbase + pass * 16 + jl;
        const float* tp = tmat + (size_t)j * 48 + b * 3;
        const float* cp = c + (size_t)j * 48 + b * 3;
        float t0 = tp[0], t1 = tp[1], t2 = tp[2];
        float c0 = cp[0], c1 = cp[1], c2 = cp[2];
        s[0] += t0*c0; s[1] += t0*c1; s[2] += t0*c2;
        s[3] += t1*c0; s[4] += t1*c1; s[5] += t1*c2;
        s[6] += t2*c0; s[7] += t2*c1; s[8] += t2*c2;
    }
    #pragma unroll
    for (int r = 0; r < 9; ++r) shred[t * 9 + r] = s[r];
    __syncthreads();
    if (t < 144) {
        int bb = t / 9, r = t % 9;
        float acc = 0.f;
        #pragma unroll
        for (int g = 0; g < 16; ++g)
            acc += shred[(g * 16 + bb) * 9 + r];
        atomicAdd(&out[t], acc);
    }
}

extern "C" void kernel_launch(void* const* d_in, const int* in_sizes, int n_in,
                              void* d_out, int out_size, void* d_ws, size_t ws_size,
                              hipStream_t stream) {
    const float* F     = (const float*)d_in[0];
    const float* pos   = (const float*)d_in[1];
    const int*   esrc  = (const int*)d_in[2];
    const int*   edst  = (const int*)d_in[3];
    const int*   etyp  = (const int*)d_in[4];
    const float* W_in  = (const float*)d_in[5];
    const float* fc1_0 = (const float*)d_in[6];
    const float* fc2_0 = (const float*)d_in[7];
    const float* W_0   = (const float*)d_in[8];
    const float* fc1_1 = (const float*)d_in[9];
    const float* fc2_1 = (const float*)d_in[10];
    const float* W_1   = (const float*)d_in[11];
    const float* W_out = (const float*)d_in[12];
    const float* w2    = (const float*)d_in[13];
    float* out = (float*)d_out;

    float* ws   = (float*)d_ws;
    float* ew   = ws;                     // 6
    float* G    = ws + 16;                // 768
    float* invF = ws + 800;               // 144
    float* bufA = ws + 1024;              // N*256
    float* bufB = bufA + N_NODES*BH;      // N*256
    float* hout = bufB + N_NODES*BH;      // N*48
    float* aArr = hout + N_NODES*48;      // N*48
    float* cArr = aArr + N_NODES*48;      // N*48
    float* tmat = cArr + N_NODES*48;      // N*48
    int* cnt    = (int*)(tmat + N_NODES*48);
    int* off    = cnt + N_NODES;          // N+1
    int* cursor = off + N_NODES + 1;      // N
    int* sedge  = cursor + N_NODES;       // E
    float* partial = (float*)(sedge + N_EDGES);  // NSTRIP * N*48 (25 MB)

    setup_kernel<<<1, 256, 0, stream>>>(F, W_in, fc1_0, fc2_0, fc1_1, fc2_1, ew, G, invF, out, cnt);
    h0_hist_kernel<<<1536, 256, 0, stream>>>(pos, G, bufA, edst, cnt);
    scan_kernel<<<1, 256, 0, stream>>>(cnt, off, cursor);
    fill_kernel<<<512, 256, 0, stream>>>(esrc, edst, etyp, cursor, sedge);
    layer_kernel<<<2048, 256, 0, stream>>>(bufA, bufB, off, sedge, ew,     W_0);
    layer_kernel<<<2048, 256, 0, stream>>>(bufB, bufA, off, sedge, ew + 3, W_1);
    hout_kernel<<<256, 256, 0, stream>>>(bufA, W_out, hout);
    ac_kernel<<<256, 256, 0, stream>>>(hout, esrc, edst, invF, aArr, cArr);
    tmat_kernel<<<512, 256, 0, stream>>>(w2, aArr, partial);
    reduce_kernel<<<192, 256, 0, stream>>>(partial, tmat);
    stress2_kernel<<<64, 256, 0, stream>>>(tmat, cArr, out);
}

// Round 6
// 232.045 us; speedup vs baseline: 1.5657x; 1.1092x over previous
//
#include <hip/hip_runtime.h>

#define N_NODES 4096
#define N_EDGES 131072
#define BATCH   16
#define HDIM    16
#define FCDIM   20
#define BH      256              // BATCH*HDIM
#define ISD     0.17677669529663687f  // 1/sqrt(E/N) = 1/sqrt(32)
#define NSTRIP  32               // tmat i-strips (128 rows each)

// f4get with COMPILE-TIME k folds to a member read (runtime k would force scratch!)
__device__ __forceinline__ float f4get(const float4& v, int k) {
    return k == 0 ? v.x : (k == 1 ? v.y : (k == 2 ? v.z : v.w));
}

// ---------------- setup: ew, G[b][j][k], invF, zero d_out + cnt -------------
__global__ void setup_kernel(const float* __restrict__ F, const float* __restrict__ W_in,
                             const float* __restrict__ fc1_0, const float* __restrict__ fc2_0,
                             const float* __restrict__ fc1_1, const float* __restrict__ fc2_1,
                             float* __restrict__ ew, float* __restrict__ G,
                             float* __restrict__ invF, float* __restrict__ out144,
                             int* __restrict__ cnt) {
    int t = threadIdx.x;
    if (t < 6) {
        const float* fc1 = (t < 3) ? fc1_0 : fc1_1;
        const float* fc2 = (t < 3) ? fc2_0 : fc2_1;
        int ty = t % 3;
        float s = 0.f;
        for (int f = 0; f < FCDIM; ++f) {
            float v = fc1[ty * FCDIM + f];
            v = v > 0.f ? v : 0.f;
            s += v * fc2[f];
        }
        ew[t] = s;
    }
    for (int idx = t; idx < BATCH * 3 * HDIM; idx += 256) {
        int b = idx / 48, r = idx % 48, j = r / HDIM, k = r % HDIM;
        float s = 0.f;
        for (int i = 0; i < 3; ++i) s += F[b * 9 + i * 3 + j] * W_in[i * HDIM + k];
        G[idx] = s;
    }
    if (t < BATCH) {
        const float* f = F + t * 9;
        float a00=f[0],a01=f[1],a02=f[2],a10=f[3],a11=f[4],a12=f[5],a20=f[6],a21=f[7],a22=f[8];
        float det = a00*(a11*a22-a12*a21) - a01*(a10*a22-a12*a20) + a02*(a10*a21-a11*a20);
        float id = 1.f/det;
        float* o = invF + t*9;
        o[0]=(a11*a22-a12*a21)*id; o[1]=(a02*a21-a01*a22)*id; o[2]=(a01*a12-a02*a11)*id;
        o[3]=(a12*a20-a10*a22)*id; o[4]=(a00*a22-a02*a20)*id; o[5]=(a02*a10-a00*a12)*id;
        o[6]=(a10*a21-a11*a20)*id; o[7]=(a01*a20-a00*a21)*id; o[8]=(a00*a11-a01*a10)*id;
    }
    if (t < 144) out144[t] = 0.f;
    for (int i = t; i < N_NODES; i += 256) cnt[i] = 0;
}

// ---------------- fused: h0 compute (blocks 0..1023) + edge hist (1024..1535)
__global__ void h0_hist_kernel(const float* __restrict__ pos, const float* __restrict__ G,
                               float* __restrict__ h0,
                               const int* __restrict__ edst, int* __restrict__ cnt) {
    int bid = blockIdx.x;
    int t = threadIdx.x;
    if (bid < 1024) {
        int id = bid * 256 + t;
        int n  = id >> 6;
        int c4 = (id & 63) << 2;
        int b  = c4 >> 4;
        int k  = c4 & 15;
        float p0 = pos[n*3+0], p1 = pos[n*3+1], p2 = pos[n*3+2];
        const float* g = G + b*48 + k;
        float4 r;
        r.x = p0*g[0] + p1*g[16] + p2*g[32];
        r.y = p0*g[1] + p1*g[17] + p2*g[33];
        r.z = p0*g[2] + p1*g[18] + p2*g[34];
        r.w = p0*g[3] + p1*g[19] + p2*g[35];
        *(float4*)(h0 + n*BH + c4) = r;
    } else {
        int e = (bid - 1024) * 256 + t;
        if (e < N_EDGES) atomicAdd(&cnt[edst[e]], 1);
    }
}

// ---------------- CSR build -------------------------------------------------
__global__ void scan_kernel(const int* __restrict__ cnt, int* __restrict__ off,
                            int* __restrict__ cursor) {
    __shared__ int wsum[4];
    int t = threadIdx.x;
    int lane = t & 63, wave = t >> 6;
    int base = t * 16;
    int loc[16];
    int s = 0;
    #pragma unroll
    for (int i = 0; i < 16; ++i) { loc[i] = s; s += cnt[base + i]; }
    // inclusive shuffle scan of s within wave
    int pre = s;
    #pragma unroll
    for (int o = 1; o < 64; o <<= 1) {
        int v = __shfl_up(pre, o);
        if (lane >= o) pre += v;
    }
    if (lane == 63) wsum[wave] = pre;
    __syncthreads();
    int woff = 0;
    #pragma unroll
    for (int w = 0; w < 4; ++w) if (w < wave) woff += wsum[w];
    int excl = woff + pre - s;
    #pragma unroll
    for (int i = 0; i < 16; ++i) {
        int v = excl + loc[i];
        off[base + i] = v;
        cursor[base + i] = v;
    }
    if (t == 255) off[N_NODES] = excl + s;
}
__global__ void fill_kernel(const int* __restrict__ src, const int* __restrict__ dst,
                            const int* __restrict__ typ, int* __restrict__ cursor,
                            int* __restrict__ sedge) {
    int e = blockIdx.x * 256 + threadIdx.x;
    if (e < N_EDGES) {
        int p = atomicAdd(&cursor[dst[e]], 1);
        sedge[p] = src[e] | (typ[e] << 16);
    }
}

// ---------------- one GCN layer: gather+scale, @W, relu ---------------------
// 2 waves per dst node (half-row each, float2 lanes); grid 2048 -> 32 waves/CU
__global__ void layer_kernel(const float* __restrict__ h_in, float* __restrict__ h_out,
                             const int* __restrict__ off, const int* __restrict__ sedge,
                             const float* __restrict__ ew3, const float* __restrict__ W) {
    __shared__ float Wl[256];
    __shared__ float aggS[2][16*17 + 4];
    int t = threadIdx.x;
    Wl[t] = W[t];
    int wave = t >> 6, lane = t & 63;
    int node = wave >> 1;
    int half = wave & 1;
    int d = blockIdx.x * 2 + node;
    float e0 = ew3[0], e1 = ew3[1], e2 = ew3[2];
    int beg = off[d], end = off[d+1];
    int col = half * 128 + lane * 2;
    float2 acc = {0.f, 0.f};
    int it = beg;
    for (; it + 7 < end; it += 8) {
        int v[8]; float2 hv[8];
        #pragma unroll
        for (int u = 0; u < 8; ++u) v[u] = sedge[it + u];
        #pragma unroll
        for (int u = 0; u < 8; ++u)
            hv[u] = *(const float2*)(h_in + (v[u] & 0xFFFF) * BH + col);
        #pragma unroll
        for (int u = 0; u < 8; ++u) {
            int ty = v[u] >> 16;
            float wg = (ty == 0) ? e0 : (ty == 1 ? e1 : e2);
            acc.x += wg * hv[u].x; acc.y += wg * hv[u].y;
        }
    }
    for (; it < end; ++it) {
        int v = sedge[it];
        int ty = v >> 16;
        float wg = (ty == 0) ? e0 : (ty == 1 ? e1 : e2);
        float2 hv = *(const float2*)(h_in + (v & 0xFFFF) * BH + col);
        acc.x += wg * hv.x; acc.y += wg * hv.y;
    }
    int b = col >> 4, k0 = col & 15;
    aggS[node][b*17 + k0]     = acc.x * ISD;
    aggS[node][b*17 + k0 + 1] = acc.y * ISD;
    __syncthreads();
    int en = t >> 7, c2 = (t & 127) * 2;
    int eb = c2 >> 4, ek = c2 & 15;
    const float* arow = aggS[en] + eb * 17;
    float o0 = 0.f, o1 = 0.f;
    #pragma unroll
    for (int k = 0; k < 16; ++k) {
        float av = arow[k];
        o0 += av * Wl[k*16 + ek];
        o1 += av * Wl[k*16 + ek + 1];
    }
    int ed = blockIdx.x * 2 + en;
    float2 r;
    r.x = o0 > 0.f ? o0 : 0.f;
    r.y = o1 > 0.f ? o1 : 0.f;
    *(float2*)(h_out + ed*BH + c2) = r;
}

// ---------------- hout[n][b*3+p] = sum_k h2[n][b*16+k] * W_out[k][p] --------
__global__ void hout_kernel(const float* __restrict__ h2, const float* __restrict__ Wout,
                            float* __restrict__ hout) {
    __shared__ float Wo[48];
    int t = threadIdx.x;
    if (t < 48) Wo[t] = Wout[t];
    __syncthreads();
    int id = blockIdx.x * 256 + t;
    int n = id >> 4, b = id & 15;
    const float* hr = h2 + n*BH + b*HDIM;
    float s0=0.f, s1=0.f, s2=0.f;
    #pragma unroll
    for (int k = 0; k < 16; ++k) {
        float v = hr[k];
        s0 += v*Wo[k*3+0]; s1 += v*Wo[k*3+1]; s2 += v*Wo[k*3+2];
    }
    float* o = hout + n*48 + b*3;
    o[0]=s0; o[1]=s1; o[2]=s2;
}

// ---------------- a, c for first N edges ------------------------------------
__global__ void ac_kernel(const float* __restrict__ hout, const int* __restrict__ esrc,
                          const int* __restrict__ edst, const float* __restrict__ invF,
                          float* __restrict__ a, float* __restrict__ c) {
    __shared__ float iF[144];
    int t = threadIdx.x;
    if (t < 144) iF[t] = invF[t];
    __syncthreads();
    int id = blockIdx.x * 256 + t;
    int i = id >> 4, b = id & 15;
    int s = esrc[i], d = edst[i];
    float a0 = hout[s*48+b*3+0] - hout[d*48+b*3+0];
    float a1 = hout[s*48+b*3+1] - hout[d*48+b*3+1];
    float a2 = hout[s*48+b*3+2] - hout[d*48+b*3+2];
    float* ap = a + i*48 + b*3;
    ap[0]=a0; ap[1]=a1; ap[2]=a2;
    const float* m = iF + b*9;
    float* cp = c + i*48 + b*3;
    cp[0] = m[0]*a0 + m[1]*a1 + m[2]*a2;
    cp[1] = m[3]*a0 + m[4]*a1 + m[5]*a2;
    cp[2] = m[6]*a0 + m[7]*a1 + m[8]*a2;
}

// ---------------- stage 1: partial[s][col][j] = sum_{i in strip s} W2[i][j]*a[i][col]
// 1024-thread blocks, 16 waves = 4 row-groups x 4 col-waves; block covers a
// 128-row strip x 256-j tile x all 48 cols. Row-groups combine via LDS
// ([col][j] layout: conflict-free b128 accesses). 48 static accumulators,
// 8-row W2 unroll (8 KB/wave in flight). Grid 512 -> 16 waves/CU.
__global__ __launch_bounds__(1024, 4)
void tmat_kernel(const float* __restrict__ W2, const float* __restrict__ a,
                 float* __restrict__ partial) {
    __shared__ float sacc[48 * 256];   // [col][j] 48 KB
    int t = threadIdx.x;
    int lane = t & 63;
    int wave = t >> 6;          // 0..15
    int cw   = wave & 3;        // col-wave
    int rg   = wave >> 2;       // row-group
    int cg   = cw * 12;
    int jb    = (blockIdx.x & 15) * 256;
    int strip = blockIdx.x >> 4;         // 0..31
    int i0    = strip * 128 + rg * 32;
    int jloc  = lane * 4;
    int j     = jb + jloc;
    const float* w2p = W2 + (size_t)i0 * N_NODES + j;
    const float* ap  = a + (size_t)i0 * 48 + cg;
    float4 acc[4][3];
    #pragma unroll
    for (int jj = 0; jj < 4; ++jj)
        #pragma unroll
        for (int q = 0; q < 3; ++q) acc[jj][q] = make_float4(0.f,0.f,0.f,0.f);
    for (int ii = 0; ii < 32; ii += 8) {
        float4 w[8];
        #pragma unroll
        for (int u = 0; u < 8; ++u)
            w[u] = *(const float4*)(w2p + (size_t)(ii + u) * N_NODES);
        #pragma unroll
        for (int u = 0; u < 8; ++u) {
            const float* ar = ap + (size_t)(ii + u) * 48;
            float4 x = *(const float4*)(ar);
            float4 y = *(const float4*)(ar + 4);
            float4 z = *(const float4*)(ar + 8);
            #pragma unroll
            for (int jj = 0; jj < 4; ++jj) {
                float wv = f4get(w[u], jj);
                acc[jj][0].x += wv*x.x; acc[jj][0].y += wv*x.y;
                acc[jj][0].z += wv*x.z; acc[jj][0].w += wv*x.w;
                acc[jj][1].x += wv*y.x; acc[jj][1].y += wv*y.y;
                acc[jj][1].z += wv*y.z; acc[jj][1].w += wv*y.w;
                acc[jj][2].x += wv*z.x; acc[jj][2].y += wv*z.y;
                acc[jj][2].z += wv*z.z; acc[jj][2].w += wv*z.w;
            }
        }
    }
    // combine 4 row-groups in LDS: sacc[col][j], j-vectorized float4 writes
    #pragma unroll 1
    for (int g = 0; g < 4; ++g) {
        if (rg == g) {
            #pragma unroll
            for (int c = 0; c < 12; ++c) {
                float4* p = (float4*)&sacc[(cg + c) * 256 + jloc];
                float4 v;
                v.x = f4get(acc[0][c >> 2], c & 3);
                v.y = f4get(acc[1][c >> 2], c & 3);
                v.z = f4get(acc[2][c >> 2], c & 3);
                v.w = f4get(acc[3][c >> 2], c & 3);
                if (g == 0) *p = v;
                else { float4 o = *p; o.x+=v.x; o.y+=v.y; o.z+=v.z; o.w+=v.w; *p = o; }
            }
        }
        __syncthreads();
    }
    // store 48x256 tile: partial[strip][col][jb..jb+256)
    float* pbase = partial + (size_t)strip * (48 * N_NODES);
    #pragma unroll
    for (int k = 0; k < 3; ++k) {
        int f = k * 1024 + t;           // 0..3071 float4s
        int col = f >> 6;
        int jl  = (f & 63) * 4;
        float4 v = *(float4*)&sacc[col * 256 + jl];
        *(float4*)(pbase + (size_t)col * N_NODES + jb + jl) = v;
    }
}

// ---------------- reduce partials: tmat[col][j] = sum_s partial[s] ----------
__global__ void reduce_kernel(const float* __restrict__ partial, float* __restrict__ tmat) {
    int x = (blockIdx.x * 64 + threadIdx.x) * 4;   // 49152 float4s, 768 blocks x 64
    float4 s = {0.f, 0.f, 0.f, 0.f};
    #pragma unroll 4
    for (int st = 0; st < NSTRIP; ++st) {
        float4 v = *(const float4*)(partial + (size_t)st * (48 * N_NODES) + x);
        s.x += v.x; s.y += v.y; s.z += v.z; s.w += v.w;
    }
    *(float4*)(tmat + x) = s;
}

// ---------------- stage 2: stress[b,p,q] = sum_j t[bp][j] * c[j][bq] --------
__global__ void stress2_kernel(const float* __restrict__ tmat, const float* __restrict__ c,
                               float* __restrict__ out) {
    __shared__ float shred[256 * 9];
    int t = threadIdx.x;
    int b = t & 15, jl = t >> 4;
    int jbase = blockIdx.x * 64;
    float s[9];
    #pragma unroll
    for (int r = 0; r < 9; ++r) s[r] = 0.f;
    for (int pass = 0; pass < 4; ++pass) {
        int j = jbase + pass * 16 + jl;
        float t0 = tmat[(size_t)(b*3+0) * N_NODES + j];
        float t1 = tmat[(size_t)(b*3+1) * N_NODES + j];
        float t2 = tmat[(size_t)(b*3+2) * N_NODES + j];
        const float* cp = c + (size_t)j * 48 + b * 3;
        float c0 = cp[0], c1 = cp[1], c2 = cp[2];
        s[0] += t0*c0; s[1] += t0*c1; s[2] += t0*c2;
        s[3] += t1*c0; s[4] += t1*c1; s[5] += t1*c2;
        s[6] += t2*c0; s[7] += t2*c1; s[8] += t2*c2;
    }
    #pragma unroll
    for (int r = 0; r < 9; ++r) shred[t * 9 + r] = s[r];
    __syncthreads();
    if (t < 144) {
        int bb = t / 9, r = t % 9;
        float acc = 0.f;
        #pragma unroll
        for (int g = 0; g < 16; ++g)
            acc += shred[(g * 16 + bb) * 9 + r];
        atomicAdd(&out[t], acc);
    }
}

extern "C" void kernel_launch(void* const* d_in, const int* in_sizes, int n_in,
                              void* d_out, int out_size, void* d_ws, size_t ws_size,
                              hipStream_t stream) {
    const float* F     = (const float*)d_in[0];
    const float* pos   = (const float*)d_in[1];
    const int*   esrc  = (const int*)d_in[2];
    const int*   edst  = (const int*)d_in[3];
    const int*   etyp  = (const int*)d_in[4];
    const float* W_in  = (const float*)d_in[5];
    const float* fc1_0 = (const float*)d_in[6];
    const float* fc2_0 = (const float*)d_in[7];
    const float* W_0   = (const float*)d_in[8];
    const float* fc1_1 = (const float*)d_in[9];
    const float* fc2_1 = (const float*)d_in[10];
    const float* W_1   = (const float*)d_in[11];
    const float* W_out = (const float*)d_in[12];
    const float* w2    = (const float*)d_in[13];
    float* out = (float*)d_out;

    float* ws   = (float*)d_ws;
    float* ew   = ws;                     // 6
    float* G    = ws + 16;                // 768
    float* invF = ws + 800;               // 144
    float* bufA = ws + 1024;              // N*256
    float* bufB = bufA + N_NODES*BH;      // N*256
    float* hout = bufB + N_NODES*BH;      // N*48
    float* aArr = hout + N_NODES*48;      // N*48
    float* cArr = aArr + N_NODES*48;      // N*48
    float* tmat = cArr + N_NODES*48;      // N*48
    int* cnt    = (int*)(tmat + N_NODES*48);
    int* off    = cnt + N_NODES;          // N+1
    int* cursor = off + N_NODES + 1;      // N
    int* sedge  = cursor + N_NODES;       // E
    float* partial = (float*)(sedge + N_EDGES);  // NSTRIP * N*48 (25 MB)

    setup_kernel<<<1, 256, 0, stream>>>(F, W_in, fc1_0, fc2_0, fc1_1, fc2_1, ew, G, invF, out, cnt);
    h0_hist_kernel<<<1536, 256, 0, stream>>>(pos, G, bufA, edst, cnt);
    scan_kernel<<<1, 256, 0, stream>>>(cnt, off, cursor);
    fill_kernel<<<512, 256, 0, stream>>>(esrc, edst, etyp, cursor, sedge);
    layer_kernel<<<2048, 256, 0, stream>>>(bufA, bufB, off, sedge, ew,     W_0);
    layer_kernel<<<2048, 256, 0, stream>>>(bufB, bufA, off, sedge, ew + 3, W_1);
    hout_kernel<<<256, 256, 0, stream>>>(bufA, W_out, hout);
    ac_kernel<<<256, 256, 0, stream>>>(hout, esrc, edst, invF, aArr, cArr);
    tmat_kernel<<<512, 1024, 0, stream>>>(w2, aArr, partial);
    reduce_kernel<<<768, 64, 0, stream>>>(partial, tmat);
    stress2_kernel<<<64, 256, 0, stream>>>(tmat, cArr, out);
}

// Round 7
// 230.578 us; speedup vs baseline: 1.5757x; 1.0064x over previous
//
#include <hip/hip_runtime.h>

#define N_NODES 4096
#define N_EDGES 131072
#define BATCH   16
#define HDIM    16
#define FCDIM   20
#define BH      256              // BATCH*HDIM
#define ISD     0.17677669529663687f  // 1/sqrt(E/N) = 1/sqrt(32)
#define NSTRIP  32               // tmat i-strips (128 rows each)

// f4get with COMPILE-TIME k folds to a member read (runtime k would force scratch!)
__device__ __forceinline__ float f4get(const float4& v, int k) {
    return k == 0 ? v.x : (k == 1 ? v.y : (k == 2 ? v.z : v.w));
}

// ---------------- setup: ew, G[b][j][k], invF, zero d_out + cnt -------------
__global__ void setup_kernel(const float* __restrict__ F, const float* __restrict__ W_in,
                             const float* __restrict__ fc1_0, const float* __restrict__ fc2_0,
                             const float* __restrict__ fc1_1, const float* __restrict__ fc2_1,
                             float* __restrict__ ew, float* __restrict__ G,
                             float* __restrict__ invF, float* __restrict__ out144,
                             int* __restrict__ cnt) {
    int t = threadIdx.x;
    if (t < 6) {
        const float* fc1 = (t < 3) ? fc1_0 : fc1_1;
        const float* fc2 = (t < 3) ? fc2_0 : fc2_1;
        int ty = t % 3;
        float s = 0.f;
        for (int f = 0; f < FCDIM; ++f) {
            float v = fc1[ty * FCDIM + f];
            v = v > 0.f ? v : 0.f;
            s += v * fc2[f];
        }
        ew[t] = s;
    }
    for (int idx = t; idx < BATCH * 3 * HDIM; idx += 256) {
        int b = idx / 48, r = idx % 48, j = r / HDIM, k = r % HDIM;
        float s = 0.f;
        for (int i = 0; i < 3; ++i) s += F[b * 9 + i * 3 + j] * W_in[i * HDIM + k];
        G[idx] = s;
    }
    if (t < BATCH) {
        const float* f = F + t * 9;
        float a00=f[0],a01=f[1],a02=f[2],a10=f[3],a11=f[4],a12=f[5],a20=f[6],a21=f[7],a22=f[8];
        float det = a00*(a11*a22-a12*a21) - a01*(a10*a22-a12*a20) + a02*(a10*a21-a11*a20);
        float id = 1.f/det;
        float* o = invF + t*9;
        o[0]=(a11*a22-a12*a21)*id; o[1]=(a02*a21-a01*a22)*id; o[2]=(a01*a12-a02*a11)*id;
        o[3]=(a12*a20-a10*a22)*id; o[4]=(a00*a22-a02*a20)*id; o[5]=(a02*a10-a00*a12)*id;
        o[6]=(a10*a21-a11*a20)*id; o[7]=(a01*a20-a00*a21)*id; o[8]=(a00*a11-a01*a10)*id;
    }
    if (t < 144) out144[t] = 0.f;
    for (int i = t; i < N_NODES; i += 256) cnt[i] = 0;
}

// ---------------- fused: h0 compute (blocks 0..1023) + edge hist (1024..1535)
__global__ void h0_hist_kernel(const float* __restrict__ pos, const float* __restrict__ G,
                               float* __restrict__ h0,
                               const int* __restrict__ edst, int* __restrict__ cnt) {
    int bid = blockIdx.x;
    int t = threadIdx.x;
    if (bid < 1024) {
        int id = bid * 256 + t;
        int n  = id >> 6;
        int c4 = (id & 63) << 2;
        int b  = c4 >> 4;
        int k  = c4 & 15;
        float p0 = pos[n*3+0], p1 = pos[n*3+1], p2 = pos[n*3+2];
        const float* g = G + b*48 + k;
        float4 r;
        r.x = p0*g[0] + p1*g[16] + p2*g[32];
        r.y = p0*g[1] + p1*g[17] + p2*g[33];
        r.z = p0*g[2] + p1*g[18] + p2*g[34];
        r.w = p0*g[3] + p1*g[19] + p2*g[35];
        *(float4*)(h0 + n*BH + c4) = r;
    } else {
        int e = (bid - 1024) * 256 + t;
        if (e < N_EDGES) atomicAdd(&cnt[edst[e]], 1);
    }
}

// ---------------- CSR build -------------------------------------------------
__global__ void scan_kernel(const int* __restrict__ cnt, int* __restrict__ off,
                            int* __restrict__ cursor) {
    __shared__ int wsum[4];
    int t = threadIdx.x;
    int lane = t & 63, wave = t >> 6;
    int base = t * 16;
    int loc[16];
    int s = 0;
    #pragma unroll
    for (int i = 0; i < 16; ++i) { loc[i] = s; s += cnt[base + i]; }
    int pre = s;
    #pragma unroll
    for (int o = 1; o < 64; o <<= 1) {
        int v = __shfl_up(pre, o);
        if (lane >= o) pre += v;
    }
    if (lane == 63) wsum[wave] = pre;
    __syncthreads();
    int woff = 0;
    #pragma unroll
    for (int w = 0; w < 4; ++w) if (w < wave) woff += wsum[w];
    int excl = woff + pre - s;
    #pragma unroll
    for (int i = 0; i < 16; ++i) {
        int v = excl + loc[i];
        off[base + i] = v;
        cursor[base + i] = v;
    }
    if (t == 255) off[N_NODES] = excl + s;
}
__global__ void fill_kernel(const int* __restrict__ src, const int* __restrict__ dst,
                            const int* __restrict__ typ, int* __restrict__ cursor,
                            int* __restrict__ sedge) {
    int e = blockIdx.x * 256 + threadIdx.x;
    if (e < N_EDGES) {
        int p = atomicAdd(&cursor[dst[e]], 1);
        sedge[p] = src[e] | (typ[e] << 16);
    }
}

// ---------------- one GCN layer: gather+scale, @W, relu ---------------------
// 2 waves per dst node (half-row each, float2 lanes); grid 2048 -> 32 waves/CU
__global__ void layer_kernel(const float* __restrict__ h_in, float* __restrict__ h_out,
                             const int* __restrict__ off, const int* __restrict__ sedge,
                             const float* __restrict__ ew3, const float* __restrict__ W) {
    __shared__ float Wl[256];
    __shared__ float aggS[2][16*17 + 4];
    int t = threadIdx.x;
    Wl[t] = W[t];
    int wave = t >> 6, lane = t & 63;
    int node = wave >> 1;
    int half = wave & 1;
    int d = blockIdx.x * 2 + node;
    float e0 = ew3[0], e1 = ew3[1], e2 = ew3[2];
    int beg = off[d], end = off[d+1];
    int col = half * 128 + lane * 2;
    float2 acc = {0.f, 0.f};
    int it = beg;
    for (; it + 7 < end; it += 8) {
        int v[8]; float2 hv[8];
        #pragma unroll
        for (int u = 0; u < 8; ++u) v[u] = sedge[it + u];
        #pragma unroll
        for (int u = 0; u < 8; ++u)
            hv[u] = *(const float2*)(h_in + (v[u] & 0xFFFF) * BH + col);
        #pragma unroll
        for (int u = 0; u < 8; ++u) {
            int ty = v[u] >> 16;
            float wg = (ty == 0) ? e0 : (ty == 1 ? e1 : e2);
            acc.x += wg * hv[u].x; acc.y += wg * hv[u].y;
        }
    }
    for (; it < end; ++it) {
        int v = sedge[it];
        int ty = v >> 16;
        float wg = (ty == 0) ? e0 : (ty == 1 ? e1 : e2);
        float2 hv = *(const float2*)(h_in + (v & 0xFFFF) * BH + col);
        acc.x += wg * hv.x; acc.y += wg * hv.y;
    }
    int b = col >> 4, k0 = col & 15;
    aggS[node][b*17 + k0]     = acc.x * ISD;
    aggS[node][b*17 + k0 + 1] = acc.y * ISD;
    __syncthreads();
    int en = t >> 7, c2 = (t & 127) * 2;
    int eb = c2 >> 4, ek = c2 & 15;
    const float* arow = aggS[en] + eb * 17;
    float o0 = 0.f, o1 = 0.f;
    #pragma unroll
    for (int k = 0; k < 16; ++k) {
        float av = arow[k];
        o0 += av * Wl[k*16 + ek];
        o1 += av * Wl[k*16 + ek + 1];
    }
    int ed = blockIdx.x * 2 + en;
    float2 r;
    r.x = o0 > 0.f ? o0 : 0.f;
    r.y = o1 > 0.f ? o1 : 0.f;
    *(float2*)(h_out + ed*BH + c2) = r;
}

// ---------------- hout[n][b*3+p] = sum_k h2[n][b*16+k] * W_out[k][p] --------
__global__ void hout_kernel(const float* __restrict__ h2, const float* __restrict__ Wout,
                            float* __restrict__ hout) {
    __shared__ float Wo[48];
    int t = threadIdx.x;
    if (t < 48) Wo[t] = Wout[t];
    __syncthreads();
    int id = blockIdx.x * 256 + t;
    int n = id >> 4, b = id & 15;
    const float* hr = h2 + n*BH + b*HDIM;
    float s0=0.f, s1=0.f, s2=0.f;
    #pragma unroll
    for (int k = 0; k < 16; ++k) {
        float v = hr[k];
        s0 += v*Wo[k*3+0]; s1 += v*Wo[k*3+1]; s2 += v*Wo[k*3+2];
    }
    float* o = hout + n*48 + b*3;
    o[0]=s0; o[1]=s1; o[2]=s2;
}

// ---------------- a, c for first N edges ------------------------------------
__global__ void ac_kernel(const float* __restrict__ hout, const int* __restrict__ esrc,
                          const int* __restrict__ edst, const float* __restrict__ invF,
                          float* __restrict__ a, float* __restrict__ c) {
    __shared__ float iF[144];
    int t = threadIdx.x;
    if (t < 144) iF[t] = invF[t];
    __syncthreads();
    int id = blockIdx.x * 256 + t;
    int i = id >> 4, b = id & 15;
    int s = esrc[i], d = edst[i];
    float a0 = hout[s*48+b*3+0] - hout[d*48+b*3+0];
    float a1 = hout[s*48+b*3+1] - hout[d*48+b*3+1];
    float a2 = hout[s*48+b*3+2] - hout[d*48+b*3+2];
    float* ap = a + i*48 + b*3;
    ap[0]=a0; ap[1]=a1; ap[2]=a2;
    const float* m = iF + b*9;
    float* cp = c + i*48 + b*3;
    cp[0] = m[0]*a0 + m[1]*a1 + m[2]*a2;
    cp[1] = m[3]*a0 + m[4]*a1 + m[5]*a2;
    cp[2] = m[6]*a0 + m[7]*a1 + m[8]*a2;
}

// ---------------- stage 1: partial[s][col][j] = sum_{i in strip s} W2[i][j]*a[i][col]
// 256-thread blocks; wave w owns cols w*12..w*12+12 for all 128 strip rows,
// lane owns 4 consecutive j. a-strip staged in LDS (lgkmcnt — decoupled from
// W2's vmcnt). W2 double-buffered 8 rows deep (wA/wB ping-pong) so 8 dwordx4
// loads stay in flight across each FMA phase. 48 static accumulators.
__global__ __launch_bounds__(256, 2)
void tmat_kernel(const float* __restrict__ W2, const float* __restrict__ a,
                 float* __restrict__ partial) {
    __shared__ float sa[128 * 48];   // 24 KB a-strip [row][col]
    int t = threadIdx.x;
    int lane = t & 63;
    int wave = t >> 6;          // 0..3
    int cg   = wave * 12;
    int jb    = (blockIdx.x & 15) * 256;
    int strip = blockIdx.x >> 4;         // 0..31
    int i0    = strip * 128;
    // stage a-strip: 6144 floats = 1536 float4
    {
        const float4* ga = (const float4*)(a + (size_t)i0 * 48);
        float4* la = (float4*)sa;
        #pragma unroll
        for (int k = 0; k < 6; ++k) la[t + k * 256] = ga[t + k * 256];
    }
    __syncthreads();
    int j = jb + lane * 4;
    const float* w2p = W2 + (size_t)i0 * N_NODES + j;
    float4 acc[4][3];
    #pragma unroll
    for (int jj = 0; jj < 4; ++jj)
        #pragma unroll
        for (int q = 0; q < 3; ++q) acc[jj][q] = make_float4(0.f,0.f,0.f,0.f);
    float4 wA[8], wB[8];
    #pragma unroll
    for (int u = 0; u < 8; ++u)
        wA[u] = *(const float4*)(w2p + (size_t)u * N_NODES);
    #pragma unroll 1
    for (int base = 0; base < 128; base += 16) {
        // prefetch rows base+8..base+16 into wB
        #pragma unroll
        for (int u = 0; u < 8; ++u) {
            int r = base + 8 + u;
            wB[u] = *(const float4*)(w2p + (size_t)r * N_NODES);
        }
        // FMA on wA (rows base..base+8), a from LDS
        #pragma unroll
        for (int u = 0; u < 8; ++u) {
            const float* ar = &sa[(base + u) * 48 + cg];
            float4 x = *(const float4*)(ar);
            float4 y = *(const float4*)(ar + 4);
            float4 z = *(const float4*)(ar + 8);
            #pragma unroll
            for (int jj = 0; jj < 4; ++jj) {
                float wv = f4get(wA[u], jj);
                acc[jj][0].x += wv*x.x; acc[jj][0].y += wv*x.y;
                acc[jj][0].z += wv*x.z; acc[jj][0].w += wv*x.w;
                acc[jj][1].x += wv*y.x; acc[jj][1].y += wv*y.y;
                acc[jj][1].z += wv*y.z; acc[jj][1].w += wv*y.w;
                acc[jj][2].x += wv*z.x; acc[jj][2].y += wv*z.y;
                acc[jj][2].z += wv*z.z; acc[jj][2].w += wv*z.w;
            }
        }
        // prefetch rows base+16..base+24 into wA (clamped; last iter wasted)
        #pragma unroll
        for (int u = 0; u < 8; ++u) {
            int r = base + 16 + u; if (r > 127) r = 127;
            wA[u] = *(const float4*)(w2p + (size_t)r * N_NODES);
        }
        // FMA on wB (rows base+8..base+16)
        #pragma unroll
        for (int u = 0; u < 8; ++u) {
            const float* ar = &sa[(base + 8 + u) * 48 + cg];
            float4 x = *(const float4*)(ar);
            float4 y = *(const float4*)(ar + 4);
            float4 z = *(const float4*)(ar + 8);
            #pragma unroll
            for (int jj = 0; jj < 4; ++jj) {
                float wv = f4get(wB[u], jj);
                acc[jj][0].x += wv*x.x; acc[jj][0].y += wv*x.y;
                acc[jj][0].z += wv*x.z; acc[jj][0].w += wv*x.w;
                acc[jj][1].x += wv*y.x; acc[jj][1].y += wv*y.y;
                acc[jj][1].z += wv*y.z; acc[jj][1].w += wv*y.w;
                acc[jj][2].x += wv*z.x; acc[jj][2].y += wv*z.y;
                acc[jj][2].z += wv*z.z; acc[jj][2].w += wv*z.w;
            }
        }
    }
    // store: partial[strip][col][j], col = cg..cg+12, transposing acc[jj] -> j-major
    float* pbase = partial + (size_t)strip * (48 * N_NODES) + jb;
    #pragma unroll
    for (int c = 0; c < 12; ++c) {
        float4 v;
        v.x = f4get(acc[0][c >> 2], c & 3);
        v.y = f4get(acc[1][c >> 2], c & 3);
        v.z = f4get(acc[2][c >> 2], c & 3);
        v.w = f4get(acc[3][c >> 2], c & 3);
        *(float4*)(pbase + (size_t)(cg + c) * N_NODES + lane * 4) = v;
    }
}

// ---------------- reduce partials: tmat[col][j] = sum_s partial[s] ----------
__global__ void reduce_kernel(const float* __restrict__ partial, float* __restrict__ tmat) {
    int x = (blockIdx.x * 64 + threadIdx.x) * 4;   // 49152 float4s, 768 blocks x 64
    float4 s = {0.f, 0.f, 0.f, 0.f};
    #pragma unroll 4
    for (int st = 0; st < NSTRIP; ++st) {
        float4 v = *(const float4*)(partial + (size_t)st * (48 * N_NODES) + x);
        s.x += v.x; s.y += v.y; s.z += v.z; s.w += v.w;
    }
    *(float4*)(tmat + x) = s;
}

// ---------------- stage 2: stress[b,p,q] = sum_j t[bp][j] * c[j][bq] --------
__global__ void stress2_kernel(const float* __restrict__ tmat, const float* __restrict__ c,
                               float* __restrict__ out) {
    __shared__ float shred[256 * 9];
    int t = threadIdx.x;
    int b = t & 15, jl = t >> 4;
    int jbase = blockIdx.x * 64;
    float s[9];
    #pragma unroll
    for (int r = 0; r < 9; ++r) s[r] = 0.f;
    for (int pass = 0; pass < 4; ++pass) {
        int j = jbase + pass * 16 + jl;
        float t0 = tmat[(size_t)(b*3+0) * N_NODES + j];
        float t1 = tmat[(size_t)(b*3+1) * N_NODES + j];
        float t2 = tmat[(size_t)(b*3+2) * N_NODES + j];
        const float* cp = c + (size_t)j * 48 + b * 3;
        float c0 = cp[0], c1 = cp[1], c2 = cp[2];
        s[0] += t0*c0; s[1] += t0*c1; s[2] += t0*c2;
        s[3] += t1*c0; s[4] += t1*c1; s[5] += t1*c2;
        s[6] += t2*c0; s[7] += t2*c1; s[8] += t2*c2;
    }
    #pragma unroll
    for (int r = 0; r < 9; ++r) shred[t * 9 + r] = s[r];
    __syncthreads();
    if (t < 144) {
        int bb = t / 9, r = t % 9;
        float acc = 0.f;
        #pragma unroll
        for (int g = 0; g < 16; ++g)
            acc += shred[(g * 16 + bb) * 9 + r];
        atomicAdd(&out[t], acc);
    }
}

extern "C" void kernel_launch(void* const* d_in, const int* in_sizes, int n_in,
                              void* d_out, int out_size, void* d_ws, size_t ws_size,
                              hipStream_t stream) {
    const float* F     = (const float*)d_in[0];
    const float* pos   = (const float*)d_in[1];
    const int*   esrc  = (const int*)d_in[2];
    const int*   edst  = (const int*)d_in[3];
    const int*   etyp  = (const int*)d_in[4];
    const float* W_in  = (const float*)d_in[5];
    const float* fc1_0 = (const float*)d_in[6];
    const float* fc2_0 = (const float*)d_in[7];
    const float* W_0   = (const float*)d_in[8];
    const float* fc1_1 = (const float*)d_in[9];
    const float* fc2_1 = (const float*)d_in[10];
    const float* W_1   = (const float*)d_in[11];
    const float* W_out = (const float*)d_in[12];
    const float* w2    = (const float*)d_in[13];
    float* out = (float*)d_out;

    float* ws   = (float*)d_ws;
    float* ew   = ws;                     // 6
    float* G    = ws + 16;                // 768
    float* invF = ws + 800;               // 144
    float* bufA = ws + 1024;              // N*256
    float* bufB = bufA + N_NODES*BH;      // N*256
    float* hout = bufB + N_NODES*BH;      // N*48
    float* aArr = hout + N_NODES*48;      // N*48
    float* cArr = aArr + N_NODES*48;      // N*48
    float* tmat = cArr + N_NODES*48;      // N*48
    int* cnt    = (int*)(tmat + N_NODES*48);
    int* off    = cnt + N_NODES;          // N+1
    int* cursor = off + N_NODES + 1;      // N
    int* sedge  = cursor + N_NODES;       // E
    float* partial = (float*)(sedge + N_EDGES);  // NSTRIP * N*48 (25 MB)

    setup_kernel<<<1, 256, 0, stream>>>(F, W_in, fc1_0, fc2_0, fc1_1, fc2_1, ew, G, invF, out, cnt);
    h0_hist_kernel<<<1536, 256, 0, stream>>>(pos, G, bufA, edst, cnt);
    scan_kernel<<<1, 256, 0, stream>>>(cnt, off, cursor);
    fill_kernel<<<512, 256, 0, stream>>>(esrc, edst, etyp, cursor, sedge);
    layer_kernel<<<2048, 256, 0, stream>>>(bufA, bufB, off, sedge, ew,     W_0);
    layer_kernel<<<2048, 256, 0, stream>>>(bufB, bufA, off, sedge, ew + 3, W_1);
    hout_kernel<<<256, 256, 0, stream>>>(bufA, W_out, hout);
    ac_kernel<<<256, 256, 0, stream>>>(hout, esrc, edst, invF, aArr, cArr);
    tmat_kernel<<<512, 256, 0, stream>>>(w2, aArr, partial);
    reduce_kernel<<<768, 64, 0, stream>>>(partial, tmat);
    stress2_kernel<<<64, 256, 0, stream>>>(tmat, cArr, out);
}

// Round 8
// 230.313 us; speedup vs baseline: 1.5775x; 1.0011x over previous
//
#include <hip/hip_runtime.h>

#define N_NODES 4096
#define N_EDGES 131072
#define BATCH   16
#define HDIM    16
#define FCDIM   20
#define BH      256              // BATCH*HDIM
#define ISD     0.17677669529663687f  // 1/sqrt(E/N) = 1/sqrt(32)
#define NSTRIP  32               // tmat i-strips (128 rows each)

// f4get with COMPILE-TIME k folds to a member read (runtime k would force scratch!)
__device__ __forceinline__ float f4get(const float4& v, int k) {
    return k == 0 ? v.x : (k == 1 ? v.y : (k == 2 ? v.z : v.w));
}

// ---------------- setup: ew, G[b][j][k], invF, zero d_out + cnt -------------
__global__ void setup_kernel(const float* __restrict__ F, const float* __restrict__ W_in,
                             const float* __restrict__ fc1_0, const float* __restrict__ fc2_0,
                             const float* __restrict__ fc1_1, const float* __restrict__ fc2_1,
                             float* __restrict__ ew, float* __restrict__ G,
                             float* __restrict__ invF, float* __restrict__ out144,
                             int* __restrict__ cnt) {
    int t = threadIdx.x;
    if (t < 6) {
        const float* fc1 = (t < 3) ? fc1_0 : fc1_1;
        const float* fc2 = (t < 3) ? fc2_0 : fc2_1;
        int ty = t % 3;
        float s = 0.f;
        for (int f = 0; f < FCDIM; ++f) {
            float v = fc1[ty * FCDIM + f];
            v = v > 0.f ? v : 0.f;
            s += v * fc2[f];
        }
        ew[t] = s;
    }
    for (int idx = t; idx < BATCH * 3 * HDIM; idx += 256) {
        int b = idx / 48, r = idx % 48, j = r / HDIM, k = r % HDIM;
        float s = 0.f;
        for (int i = 0; i < 3; ++i) s += F[b * 9 + i * 3 + j] * W_in[i * HDIM + k];
        G[idx] = s;
    }
    if (t < BATCH) {
        const float* f = F + t * 9;
        float a00=f[0],a01=f[1],a02=f[2],a10=f[3],a11=f[4],a12=f[5],a20=f[6],a21=f[7],a22=f[8];
        float det = a00*(a11*a22-a12*a21) - a01*(a10*a22-a12*a20) + a02*(a10*a21-a11*a20);
        float id = 1.f/det;
        float* o = invF + t*9;
        o[0]=(a11*a22-a12*a21)*id; o[1]=(a02*a21-a01*a22)*id; o[2]=(a01*a12-a02*a11)*id;
        o[3]=(a12*a20-a10*a22)*id; o[4]=(a00*a22-a02*a20)*id; o[5]=(a02*a10-a00*a12)*id;
        o[6]=(a10*a21-a11*a20)*id; o[7]=(a01*a20-a00*a21)*id; o[8]=(a00*a11-a01*a10)*id;
    }
    if (t < 144) out144[t] = 0.f;
    for (int i = t; i < N_NODES; i += 256) cnt[i] = 0;
}

// ---------------- fused: h0 compute (blocks 0..1023) + edge hist (1024..1535)
__global__ void h0_hist_kernel(const float* __restrict__ pos, const float* __restrict__ G,
                               float* __restrict__ h0,
                               const int* __restrict__ edst, int* __restrict__ cnt) {
    int bid = blockIdx.x;
    int t = threadIdx.x;
    if (bid < 1024) {
        int id = bid * 256 + t;
        int n  = id >> 6;
        int c4 = (id & 63) << 2;
        int b  = c4 >> 4;
        int k  = c4 & 15;
        float p0 = pos[n*3+0], p1 = pos[n*3+1], p2 = pos[n*3+2];
        const float* g = G + b*48 + k;
        float4 r;
        r.x = p0*g[0] + p1*g[16] + p2*g[32];
        r.y = p0*g[1] + p1*g[17] + p2*g[33];
        r.z = p0*g[2] + p1*g[18] + p2*g[34];
        r.w = p0*g[3] + p1*g[19] + p2*g[35];
        *(float4*)(h0 + n*BH + c4) = r;
    } else {
        int e = (bid - 1024) * 256 + t;
        if (e < N_EDGES) atomicAdd(&cnt[edst[e]], 1);
    }
}

// ---------------- CSR build -------------------------------------------------
__global__ void scan_kernel(const int* __restrict__ cnt, int* __restrict__ off,
                            int* __restrict__ cursor) {
    __shared__ int wsum[4];
    int t = threadIdx.x;
    int lane = t & 63, wave = t >> 6;
    int base = t * 16;
    int loc[16];
    int s = 0;
    #pragma unroll
    for (int i = 0; i < 16; ++i) { loc[i] = s; s += cnt[base + i]; }
    int pre = s;
    #pragma unroll
    for (int o = 1; o < 64; o <<= 1) {
        int v = __shfl_up(pre, o);
        if (lane >= o) pre += v;
    }
    if (lane == 63) wsum[wave] = pre;
    __syncthreads();
    int woff = 0;
    #pragma unroll
    for (int w = 0; w < 4; ++w) if (w < wave) woff += wsum[w];
    int excl = woff + pre - s;
    #pragma unroll
    for (int i = 0; i < 16; ++i) {
        int v = excl + loc[i];
        off[base + i] = v;
        cursor[base + i] = v;
    }
    if (t == 255) off[N_NODES] = excl + s;
}
__global__ void fill_kernel(const int* __restrict__ src, const int* __restrict__ dst,
                            const int* __restrict__ typ, int* __restrict__ cursor,
                            int* __restrict__ sedge) {
    int e = blockIdx.x * 256 + threadIdx.x;
    if (e < N_EDGES) {
        int p = atomicAdd(&cursor[dst[e]], 1);
        sedge[p] = src[e] | (typ[e] << 16);
    }
}

// ---------------- one GCN layer: gather+scale, @W, relu ---------------------
// 2 waves per dst node (half-row each, float2 lanes); grid 2048 -> 32 waves/CU
__global__ void layer_kernel(const float* __restrict__ h_in, float* __restrict__ h_out,
                             const int* __restrict__ off, const int* __restrict__ sedge,
                             const float* __restrict__ ew3, const float* __restrict__ W) {
    __shared__ float Wl[256];
    __shared__ float aggS[2][16*17 + 4];
    int t = threadIdx.x;
    Wl[t] = W[t];
    int wave = t >> 6, lane = t & 63;
    int node = wave >> 1;
    int half = wave & 1;
    int d = blockIdx.x * 2 + node;
    float e0 = ew3[0], e1 = ew3[1], e2 = ew3[2];
    int beg = off[d], end = off[d+1];
    int col = half * 128 + lane * 2;
    float2 acc = {0.f, 0.f};
    int it = beg;
    for (; it + 7 < end; it += 8) {
        int v[8]; float2 hv[8];
        #pragma unroll
        for (int u = 0; u < 8; ++u) v[u] = sedge[it + u];
        #pragma unroll
        for (int u = 0; u < 8; ++u)
            hv[u] = *(const float2*)(h_in + (v[u] & 0xFFFF) * BH + col);
        #pragma unroll
        for (int u = 0; u < 8; ++u) {
            int ty = v[u] >> 16;
            float wg = (ty == 0) ? e0 : (ty == 1 ? e1 : e2);
            acc.x += wg * hv[u].x; acc.y += wg * hv[u].y;
        }
    }
    for (; it < end; ++it) {
        int v = sedge[it];
        int ty = v >> 16;
        float wg = (ty == 0) ? e0 : (ty == 1 ? e1 : e2);
        float2 hv = *(const float2*)(h_in + (v & 0xFFFF) * BH + col);
        acc.x += wg * hv.x; acc.y += wg * hv.y;
    }
    int b = col >> 4, k0 = col & 15;
    aggS[node][b*17 + k0]     = acc.x * ISD;
    aggS[node][b*17 + k0 + 1] = acc.y * ISD;
    __syncthreads();
    int en = t >> 7, c2 = (t & 127) * 2;
    int eb = c2 >> 4, ek = c2 & 15;
    const float* arow = aggS[en] + eb * 17;
    float o0 = 0.f, o1 = 0.f;
    #pragma unroll
    for (int k = 0; k < 16; ++k) {
        float av = arow[k];
        o0 += av * Wl[k*16 + ek];
        o1 += av * Wl[k*16 + ek + 1];
    }
    int ed = blockIdx.x * 2 + en;
    float2 r;
    r.x = o0 > 0.f ? o0 : 0.f;
    r.y = o1 > 0.f ? o1 : 0.f;
    *(float2*)(h_out + ed*BH + c2) = r;
}

// ---------------- hout[n][b*3+p] = sum_k h2[n][b*16+k] * W_out[k][p] --------
__global__ void hout_kernel(const float* __restrict__ h2, const float* __restrict__ Wout,
                            float* __restrict__ hout) {
    __shared__ float Wo[48];
    int t = threadIdx.x;
    if (t < 48) Wo[t] = Wout[t];
    __syncthreads();
    int id = blockIdx.x * 256 + t;
    int n = id >> 4, b = id & 15;
    const float* hr = h2 + n*BH + b*HDIM;
    float s0=0.f, s1=0.f, s2=0.f;
    #pragma unroll
    for (int k = 0; k < 16; ++k) {
        float v = hr[k];
        s0 += v*Wo[k*3+0]; s1 += v*Wo[k*3+1]; s2 += v*Wo[k*3+2];
    }
    float* o = hout + n*48 + b*3;
    o[0]=s0; o[1]=s1; o[2]=s2;
}

// ---------------- a, c for first N edges ------------------------------------
__global__ void ac_kernel(const float* __restrict__ hout, const int* __restrict__ esrc,
                          const int* __restrict__ edst, const float* __restrict__ invF,
                          float* __restrict__ a, float* __restrict__ c) {
    __shared__ float iF[144];
    int t = threadIdx.x;
    if (t < 144) iF[t] = invF[t];
    __syncthreads();
    int id = blockIdx.x * 256 + t;
    int i = id >> 4, b = id & 15;
    int s = esrc[i], d = edst[i];
    float a0 = hout[s*48+b*3+0] - hout[d*48+b*3+0];
    float a1 = hout[s*48+b*3+1] - hout[d*48+b*3+1];
    float a2 = hout[s*48+b*3+2] - hout[d*48+b*3+2];
    float* ap = a + i*48 + b*3;
    ap[0]=a0; ap[1]=a1; ap[2]=a2;
    const float* m = iF + b*9;
    float* cp = c + i*48 + b*3;
    cp[0] = m[0]*a0 + m[1]*a1 + m[2]*a2;
    cp[1] = m[3]*a0 + m[4]*a1 + m[5]*a2;
    cp[2] = m[6]*a0 + m[7]*a1 + m[8]*a2;
}

// ---------------- stage 1: partial[s][col][j] = sum_{i in strip s} W2[i][j]*a[i][col]
// 256-thread blocks; wave w owns cols w*12..w*12+12 for all 128 strip rows,
// lane owns 4 consecutive j (dwordx4 W2 loads). a-strip in LDS (lgkmcnt,
// decoupled from W2's vmcnt). 4-row rotating prefetch: w[4]+wn[4] = 32 VGPRs
// of buffer + 48 acc keeps the whole hot set in ARCH VGPRs (~95) -- R7's
// 8-deep dbuf (64 buf VGPRs) pushed acc into AGPRs and broke the pipeline.
__global__ __launch_bounds__(256, 2)
void tmat_kernel(const float* __restrict__ W2, const float* __restrict__ a,
                 float* __restrict__ partial) {
    __shared__ float sa[128 * 48];   // 24 KB a-strip [row][col]
    int t = threadIdx.x;
    int lane = t & 63;
    int wave = t >> 6;          // 0..3
    int cg   = wave * 12;
    int jb    = (blockIdx.x & 15) * 256;
    int strip = blockIdx.x >> 4;         // 0..31
    int i0    = strip * 128;
    // stage a-strip: 6144 floats = 1536 float4
    {
        const float4* ga = (const float4*)(a + (size_t)i0 * 48);
        float4* la = (float4*)sa;
        #pragma unroll
        for (int k = 0; k < 6; ++k) la[t + k * 256] = ga[t + k * 256];
    }
    __syncthreads();
    int j = jb + lane * 4;
    const float* w2p = W2 + (size_t)i0 * N_NODES + j;
    float4 acc[4][3];
    #pragma unroll
    for (int jj = 0; jj < 4; ++jj)
        #pragma unroll
        for (int q = 0; q < 3; ++q) acc[jj][q] = make_float4(0.f,0.f,0.f,0.f);
    float4 w[4];
    #pragma unroll
    for (int u = 0; u < 4; ++u)
        w[u] = *(const float4*)(w2p + (size_t)u * N_NODES);
    #pragma unroll 1
    for (int base = 0; base < 128; base += 4) {
        // prefetch next 4 rows (clamped on last iter; wasted loads are harmless)
        float4 wn[4];
        #pragma unroll
        for (int u = 0; u < 4; ++u) {
            int r = base + 4 + u; if (r > 127) r = 127;
            wn[u] = *(const float4*)(w2p + (size_t)r * N_NODES);
        }
        // FMA on current 4 rows, a from LDS
        #pragma unroll
        for (int u = 0; u < 4; ++u) {
            const float* ar = &sa[(base + u) * 48 + cg];
            float4 x = *(const float4*)(ar);
            float4 y = *(const float4*)(ar + 4);
            float4 z = *(const float4*)(ar + 8);
            #pragma unroll
            for (int jj = 0; jj < 4; ++jj) {
                float wv = f4get(w[u], jj);
                acc[jj][0].x += wv*x.x; acc[jj][0].y += wv*x.y;
                acc[jj][0].z += wv*x.z; acc[jj][0].w += wv*x.w;
                acc[jj][1].x += wv*y.x; acc[jj][1].y += wv*y.y;
                acc[jj][1].z += wv*y.z; acc[jj][1].w += wv*y.w;
                acc[jj][2].x += wv*z.x; acc[jj][2].y += wv*z.y;
                acc[jj][2].z += wv*z.z; acc[jj][2].w += wv*z.w;
            }
        }
        #pragma unroll
        for (int u = 0; u < 4; ++u) w[u] = wn[u];
    }
    // store: partial[strip][col][j], col = cg..cg+12, transposing acc[jj] -> j-major
    float* pbase = partial + (size_t)strip * (48 * N_NODES) + jb;
    #pragma unroll
    for (int c = 0; c < 12; ++c) {
        float4 v;
        v.x = f4get(acc[0][c >> 2], c & 3);
        v.y = f4get(acc[1][c >> 2], c & 3);
        v.z = f4get(acc[2][c >> 2], c & 3);
        v.w = f4get(acc[3][c >> 2], c & 3);
        *(float4*)(pbase + (size_t)(cg + c) * N_NODES + lane * 4) = v;
    }
}

// ---------------- reduce partials: tmat[col][j] = sum_s partial[s] ----------
__global__ void reduce_kernel(const float* __restrict__ partial, float* __restrict__ tmat) {
    int x = (blockIdx.x * 64 + threadIdx.x) * 4;   // 49152 float4s, 768 blocks x 64
    float4 s = {0.f, 0.f, 0.f, 0.f};
    #pragma unroll 4
    for (int st = 0; st < NSTRIP; ++st) {
        float4 v = *(const float4*)(partial + (size_t)st * (48 * N_NODES) + x);
        s.x += v.x; s.y += v.y; s.z += v.z; s.w += v.w;
    }
    *(float4*)(tmat + x) = s;
}

// ---------------- stage 2: stress[b,p,q] = sum_j t[bp][j] * c[j][bq] --------
__global__ void stress2_kernel(const float* __restrict__ tmat, const float* __restrict__ c,
                               float* __restrict__ out) {
    __shared__ float shred[256 * 9];
    int t = threadIdx.x;
    int b = t & 15, jl = t >> 4;
    int jbase = blockIdx.x * 64;
    float s[9];
    #pragma unroll
    for (int r = 0; r < 9; ++r) s[r] = 0.f;
    for (int pass = 0; pass < 4; ++pass) {
        int j = jbase + pass * 16 + jl;
        float t0 = tmat[(size_t)(b*3+0) * N_NODES + j];
        float t1 = tmat[(size_t)(b*3+1) * N_NODES + j];
        float t2 = tmat[(size_t)(b*3+2) * N_NODES + j];
        const float* cp = c + (size_t)j * 48 + b * 3;
        float c0 = cp[0], c1 = cp[1], c2 = cp[2];
        s[0] += t0*c0; s[1] += t0*c1; s[2] += t0*c2;
        s[3] += t1*c0; s[4] += t1*c1; s[5] += t1*c2;
        s[6] += t2*c0; s[7] += t2*c1; s[8] += t2*c2;
    }
    #pragma unroll
    for (int r = 0; r < 9; ++r) shred[t * 9 + r] = s[r];
    __syncthreads();
    if (t < 144) {
        int bb = t / 9, r = t % 9;
        float acc = 0.f;
        #pragma unroll
        for (int g = 0; g < 16; ++g)
            acc += shred[(g * 16 + bb) * 9 + r];
        atomicAdd(&out[t], acc);
    }
}

extern "C" void kernel_launch(void* const* d_in, const int* in_sizes, int n_in,
                              void* d_out, int out_size, void* d_ws, size_t ws_size,
                              hipStream_t stream) {
    const float* F     = (const float*)d_in[0];
    const float* pos   = (const float*)d_in[1];
    const int*   esrc  = (const int*)d_in[2];
    const int*   edst  = (const int*)d_in[3];
    const int*   etyp  = (const int*)d_in[4];
    const float* W_in  = (const float*)d_in[5];
    const float* fc1_0 = (const float*)d_in[6];
    const float* fc2_0 = (const float*)d_in[7];
    const float* W_0   = (const float*)d_in[8];
    const float* fc1_1 = (const float*)d_in[9];
    const float* fc2_1 = (const float*)d_in[10];
    const float* W_1   = (const float*)d_in[11];
    const float* W_out = (const float*)d_in[12];
    const float* w2    = (const float*)d_in[13];
    float* out = (float*)d_out;

    float* ws   = (float*)d_ws;
    float* ew   = ws;                     // 6
    float* G    = ws + 16;                // 768
    float* invF = ws + 800;               // 144
    float* bufA = ws + 1024;              // N*256
    float* bufB = bufA + N_NODES*BH;      // N*256
    float* hout = bufB + N_NODES*BH;      // N*48
    float* aArr = hout + N_NODES*48;      // N*48
    float* cArr = aArr + N_NODES*48;      // N*48
    float* tmat = cArr + N_NODES*48;      // N*48
    int* cnt    = (int*)(tmat + N_NODES*48);
    int* off    = cnt + N_NODES;          // N+1
    int* cursor = off + N_NODES + 1;      // N
    int* sedge  = cursor + N_NODES;       // E
    float* partial = (float*)(sedge + N_EDGES);  // NSTRIP * N*48 (25 MB)

    setup_kernel<<<1, 256, 0, stream>>>(F, W_in, fc1_0, fc2_0, fc1_1, fc2_1, ew, G, invF, out, cnt);
    h0_hist_kernel<<<1536, 256, 0, stream>>>(pos, G, bufA, edst, cnt);
    scan_kernel<<<1, 256, 0, stream>>>(cnt, off, cursor);
    fill_kernel<<<512, 256, 0, stream>>>(esrc, edst, etyp, cursor, sedge);
    layer_kernel<<<2048, 256, 0, stream>>>(bufA, bufB, off, sedge, ew,     W_0);
    layer_kernel<<<2048, 256, 0, stream>>>(bufB, bufA, off, sedge, ew + 3, W_1);
    hout_kernel<<<256, 256, 0, stream>>>(bufA, W_out, hout);
    ac_kernel<<<256, 256, 0, stream>>>(hout, esrc, edst, invF, aArr, cArr);
    tmat_kernel<<<512, 256, 0, stream>>>(w2, aArr, partial);
    reduce_kernel<<<768, 64, 0, stream>>>(partial, tmat);
    stress2_kernel<<<64, 256, 0, stream>>>(tmat, cArr, out);
}

// Round 9
// 215.057 us; speedup vs baseline: 1.6894x; 1.0709x over previous
//
#include <hip/hip_runtime.h>

#define N_NODES 4096
#define N_EDGES 131072
#define BATCH   16
#define HDIM    16
#define FCDIM   20
#define BH      256              // BATCH*HDIM
#define ISD     0.17677669529663687f  // 1/sqrt(E/N) = 1/sqrt(32)
#define NSTRIP  32               // tmat i-strips (128 rows each)

// f4get with COMPILE-TIME k folds to a member read (runtime k would force scratch!)
__device__ __forceinline__ float f4get(const float4& v, int k) {
    return k == 0 ? v.x : (k == 1 ? v.y : (k == 2 ? v.z : v.w));
}

// ---------------- setup: ew, G[b][j][k], invF, zero d_out + cnt -------------
__global__ void setup_kernel(const float* __restrict__ F, const float* __restrict__ W_in,
                             const float* __restrict__ fc1_0, const float* __restrict__ fc2_0,
                             const float* __restrict__ fc1_1, const float* __restrict__ fc2_1,
                             float* __restrict__ ew, float* __restrict__ G,
                             float* __restrict__ invF, float* __restrict__ out144,
                             int* __restrict__ cnt) {
    int t = threadIdx.x;
    if (t < 6) {
        const float* fc1 = (t < 3) ? fc1_0 : fc1_1;
        const float* fc2 = (t < 3) ? fc2_0 : fc2_1;
        int ty = t % 3;
        float s = 0.f;
        for (int f = 0; f < FCDIM; ++f) {
            float v = fc1[ty * FCDIM + f];
            v = v > 0.f ? v : 0.f;
            s += v * fc2[f];
        }
        ew[t] = s;
    }
    for (int idx = t; idx < BATCH * 3 * HDIM; idx += 256) {
        int b = idx / 48, r = idx % 48, j = r / HDIM, k = r % HDIM;
        float s = 0.f;
        for (int i = 0; i < 3; ++i) s += F[b * 9 + i * 3 + j] * W_in[i * HDIM + k];
        G[idx] = s;
    }
    if (t < BATCH) {
        const float* f = F + t * 9;
        float a00=f[0],a01=f[1],a02=f[2],a10=f[3],a11=f[4],a12=f[5],a20=f[6],a21=f[7],a22=f[8];
        float det = a00*(a11*a22-a12*a21) - a01*(a10*a22-a12*a20) + a02*(a10*a21-a11*a20);
        float id = 1.f/det;
        float* o = invF + t*9;
        o[0]=(a11*a22-a12*a21)*id; o[1]=(a02*a21-a01*a22)*id; o[2]=(a01*a12-a02*a11)*id;
        o[3]=(a12*a20-a10*a22)*id; o[4]=(a00*a22-a02*a20)*id; o[5]=(a02*a10-a00*a12)*id;
        o[6]=(a10*a21-a11*a20)*id; o[7]=(a01*a20-a00*a21)*id; o[8]=(a00*a11-a01*a10)*id;
    }
    if (t < 144) out144[t] = 0.f;
    for (int i = t; i < N_NODES; i += 256) cnt[i] = 0;
}

// ---------------- fused: h0 compute (blocks 0..1023) + edge hist (1024..1535)
__global__ void h0_hist_kernel(const float* __restrict__ pos, const float* __restrict__ G,
                               float* __restrict__ h0,
                               const int* __restrict__ edst, int* __restrict__ cnt) {
    int bid = blockIdx.x;
    int t = threadIdx.x;
    if (bid < 1024) {
        int id = bid * 256 + t;
        int n  = id >> 6;
        int c4 = (id & 63) << 2;
        int b  = c4 >> 4;
        int k  = c4 & 15;
        float p0 = pos[n*3+0], p1 = pos[n*3+1], p2 = pos[n*3+2];
        const float* g = G + b*48 + k;
        float4 r;
        r.x = p0*g[0] + p1*g[16] + p2*g[32];
        r.y = p0*g[1] + p1*g[17] + p2*g[33];
        r.z = p0*g[2] + p1*g[18] + p2*g[34];
        r.w = p0*g[3] + p1*g[19] + p2*g[35];
        *(float4*)(h0 + n*BH + c4) = r;
    } else {
        int e = (bid - 1024) * 256 + t;
        if (e < N_EDGES) atomicAdd(&cnt[edst[e]], 1);
    }
}

// ---------------- CSR build -------------------------------------------------
__global__ void scan_kernel(const int* __restrict__ cnt, int* __restrict__ off,
                            int* __restrict__ cursor) {
    __shared__ int wsum[4];
    int t = threadIdx.x;
    int lane = t & 63, wave = t >> 6;
    int base = t * 16;
    int loc[16];
    int s = 0;
    #pragma unroll
    for (int i = 0; i < 16; ++i) { loc[i] = s; s += cnt[base + i]; }
    int pre = s;
    #pragma unroll
    for (int o = 1; o < 64; o <<= 1) {
        int v = __shfl_up(pre, o);
        if (lane >= o) pre += v;
    }
    if (lane == 63) wsum[wave] = pre;
    __syncthreads();
    int woff = 0;
    #pragma unroll
    for (int w = 0; w < 4; ++w) if (w < wave) woff += wsum[w];
    int excl = woff + pre - s;
    #pragma unroll
    for (int i = 0; i < 16; ++i) {
        int v = excl + loc[i];
        off[base + i] = v;
        cursor[base + i] = v;
    }
    if (t == 255) off[N_NODES] = excl + s;
}
__global__ void fill_kernel(const int* __restrict__ src, const int* __restrict__ dst,
                            const int* __restrict__ typ, int* __restrict__ cursor,
                            int* __restrict__ sedge) {
    int e = blockIdx.x * 256 + threadIdx.x;
    if (e < N_EDGES) {
        int p = atomicAdd(&cursor[dst[e]], 1);
        sedge[p] = src[e] | (typ[e] << 16);
    }
}

// ---------------- one GCN layer: gather+scale, @W, relu ---------------------
// 2 waves per dst node (half-row each, float2 lanes); grid 2048 -> 32 waves/CU
__global__ void layer_kernel(const float* __restrict__ h_in, float* __restrict__ h_out,
                             const int* __restrict__ off, const int* __restrict__ sedge,
                             const float* __restrict__ ew3, const float* __restrict__ W) {
    __shared__ float Wl[256];
    __shared__ float aggS[2][16*17 + 4];
    int t = threadIdx.x;
    Wl[t] = W[t];
    int wave = t >> 6, lane = t & 63;
    int node = wave >> 1;
    int half = wave & 1;
    int d = blockIdx.x * 2 + node;
    float e0 = ew3[0], e1 = ew3[1], e2 = ew3[2];
    int beg = off[d], end = off[d+1];
    int col = half * 128 + lane * 2;
    float2 acc = {0.f, 0.f};
    int it = beg;
    for (; it + 7 < end; it += 8) {
        int v[8]; float2 hv[8];
        #pragma unroll
        for (int u = 0; u < 8; ++u) v[u] = sedge[it + u];
        #pragma unroll
        for (int u = 0; u < 8; ++u)
            hv[u] = *(const float2*)(h_in + (v[u] & 0xFFFF) * BH + col);
        #pragma unroll
        for (int u = 0; u < 8; ++u) {
            int ty = v[u] >> 16;
            float wg = (ty == 0) ? e0 : (ty == 1 ? e1 : e2);
            acc.x += wg * hv[u].x; acc.y += wg * hv[u].y;
        }
    }
    for (; it < end; ++it) {
        int v = sedge[it];
        int ty = v >> 16;
        float wg = (ty == 0) ? e0 : (ty == 1 ? e1 : e2);
        float2 hv = *(const float2*)(h_in + (v & 0xFFFF) * BH + col);
        acc.x += wg * hv.x; acc.y += wg * hv.y;
    }
    int b = col >> 4, k0 = col & 15;
    aggS[node][b*17 + k0]     = acc.x * ISD;
    aggS[node][b*17 + k0 + 1] = acc.y * ISD;
    __syncthreads();
    int en = t >> 7, c2 = (t & 127) * 2;
    int eb = c2 >> 4, ek = c2 & 15;
    const float* arow = aggS[en] + eb * 17;
    float o0 = 0.f, o1 = 0.f;
    #pragma unroll
    for (int k = 0; k < 16; ++k) {
        float av = arow[k];
        o0 += av * Wl[k*16 + ek];
        o1 += av * Wl[k*16 + ek + 1];
    }
    int ed = blockIdx.x * 2 + en;
    float2 r;
    r.x = o0 > 0.f ? o0 : 0.f;
    r.y = o1 > 0.f ? o1 : 0.f;
    *(float2*)(h_out + ed*BH + c2) = r;
}

// ---------------- hout[n][b*3+p] = sum_k h2[n][b*16+k] * W_out[k][p] --------
__global__ void hout_kernel(const float* __restrict__ h2, const float* __restrict__ Wout,
                            float* __restrict__ hout) {
    __shared__ float Wo[48];
    int t = threadIdx.x;
    if (t < 48) Wo[t] = Wout[t];
    __syncthreads();
    int id = blockIdx.x * 256 + t;
    int n = id >> 4, b = id & 15;
    const float* hr = h2 + n*BH + b*HDIM;
    float s0=0.f, s1=0.f, s2=0.f;
    #pragma unroll
    for (int k = 0; k < 16; ++k) {
        float v = hr[k];
        s0 += v*Wo[k*3+0]; s1 += v*Wo[k*3+1]; s2 += v*Wo[k*3+2];
    }
    float* o = hout + n*48 + b*3;
    o[0]=s0; o[1]=s1; o[2]=s2;
}

// ---------------- a, c for first N edges ------------------------------------
__global__ void ac_kernel(const float* __restrict__ hout, const int* __restrict__ esrc,
                          const int* __restrict__ edst, const float* __restrict__ invF,
                          float* __restrict__ a, float* __restrict__ c) {
    __shared__ float iF[144];
    int t = threadIdx.x;
    if (t < 144) iF[t] = invF[t];
    __syncthreads();
    int id = blockIdx.x * 256 + t;
    int i = id >> 4, b = id & 15;
    int s = esrc[i], d = edst[i];
    float a0 = hout[s*48+b*3+0] - hout[d*48+b*3+0];
    float a1 = hout[s*48+b*3+1] - hout[d*48+b*3+1];
    float a2 = hout[s*48+b*3+2] - hout[d*48+b*3+2];
    float* ap = a + i*48 + b*3;
    ap[0]=a0; ap[1]=a1; ap[2]=a2;
    const float* m = iF + b*9;
    float* cp = c + i*48 + b*3;
    cp[0] = m[0]*a0 + m[1]*a1 + m[2]*a2;
    cp[1] = m[3]*a0 + m[4]*a1 + m[5]*a2;
    cp[2] = m[6]*a0 + m[7]*a1 + m[8]*a2;
}

// ---------------- stage 1: partial[s][col][j] = sum_{i in strip s} W2[i][j]*a[i][col]
// grid 1024 = 32 j-tiles(128 j) x 32 i-strips(128 rows) -> 4 blocks/CU,
// 16 waves/CU (the R8 grid of 512 capped occupancy at 2 blocks/CU = the
// pinned 21% VALUBusy). Wave w owns cols w*12..w*12+12; lane owns 2 j
// (dwordx2 W2 loads). a-strip in LDS (lgkmcnt). 8-row rotating prefetch
// (w[8]+wn[8] float2 = 32 buffer VGPRs), 24 static accumulators.
__global__ __launch_bounds__(256, 4)
void tmat_kernel(const float* __restrict__ W2, const float* __restrict__ a,
                 float* __restrict__ partial) {
    __shared__ float sa[128 * 48];   // 24 KB a-strip [row][col]
    int t = threadIdx.x;
    int lane = t & 63;
    int wave = t >> 6;          // 0..3
    int cg   = wave * 12;
    int jb    = (blockIdx.x & 31) * 128;
    int strip = blockIdx.x >> 5;         // 0..31
    int i0    = strip * 128;
    // stage a-strip: 6144 floats = 1536 float4
    {
        const float4* ga = (const float4*)(a + (size_t)i0 * 48);
        float4* la = (float4*)sa;
        #pragma unroll
        for (int k = 0; k < 6; ++k) la[t + k * 256] = ga[t + k * 256];
    }
    __syncthreads();
    int j = jb + lane * 2;
    const float* w2p = W2 + (size_t)i0 * N_NODES + j;
    float4 acc[2][3];
    #pragma unroll
    for (int jj = 0; jj < 2; ++jj)
        #pragma unroll
        for (int q = 0; q < 3; ++q) acc[jj][q] = make_float4(0.f,0.f,0.f,0.f);
    float2 w[8];
    #pragma unroll
    for (int u = 0; u < 8; ++u)
        w[u] = *(const float2*)(w2p + (size_t)u * N_NODES);
    #pragma unroll 1
    for (int base = 0; base < 128; base += 8) {
        // prefetch next 8 rows (clamped on last iter; wasted loads are harmless)
        float2 wn[8];
        #pragma unroll
        for (int u = 0; u < 8; ++u) {
            int r = base + 8 + u; if (r > 127) r = 127;
            wn[u] = *(const float2*)(w2p + (size_t)r * N_NODES);
        }
        // FMA on current 8 rows, a from LDS
        #pragma unroll
        for (int u = 0; u < 8; ++u) {
            const float* ar = &sa[(base + u) * 48 + cg];
            float4 x = *(const float4*)(ar);
            float4 y = *(const float4*)(ar + 4);
            float4 z = *(const float4*)(ar + 8);
            #pragma unroll
            for (int jj = 0; jj < 2; ++jj) {
                float wv = jj == 0 ? w[u].x : w[u].y;
                acc[jj][0].x += wv*x.x; acc[jj][0].y += wv*x.y;
                acc[jj][0].z += wv*x.z; acc[jj][0].w += wv*x.w;
                acc[jj][1].x += wv*y.x; acc[jj][1].y += wv*y.y;
                acc[jj][1].z += wv*y.z; acc[jj][1].w += wv*y.w;
                acc[jj][2].x += wv*z.x; acc[jj][2].y += wv*z.y;
                acc[jj][2].z += wv*z.z; acc[jj][2].w += wv*z.w;
            }
        }
        #pragma unroll
        for (int u = 0; u < 8; ++u) w[u] = wn[u];
    }
    // store: partial[strip][col][j], col = cg..cg+12 (float2 per col)
    float* pbase = partial + (size_t)strip * (48 * N_NODES) + jb;
    #pragma unroll
    for (int c = 0; c < 12; ++c) {
        float2 v;
        v.x = f4get(acc[0][c >> 2], c & 3);
        v.y = f4get(acc[1][c >> 2], c & 3);
        *(float2*)(pbase + (size_t)(cg + c) * N_NODES + lane * 2) = v;
    }
}

// ---------------- reduce partials: tmat[col][j] = sum_s partial[s] ----------
__global__ void reduce_kernel(const float* __restrict__ partial, float* __restrict__ tmat) {
    int x = (blockIdx.x * 64 + threadIdx.x) * 4;   // 49152 float4s, 768 blocks x 64
    float4 s = {0.f, 0.f, 0.f, 0.f};
    #pragma unroll 4
    for (int st = 0; st < NSTRIP; ++st) {
        float4 v = *(const float4*)(partial + (size_t)st * (48 * N_NODES) + x);
        s.x += v.x; s.y += v.y; s.z += v.z; s.w += v.w;
    }
    *(float4*)(tmat + x) = s;
}

// ---------------- stage 2: stress[b,p,q] = sum_j t[bp][j] * c[j][bq] --------
__global__ void stress2_kernel(const float* __restrict__ tmat, const float* __restrict__ c,
                               float* __restrict__ out) {
    __shared__ float shred[256 * 9];
    int t = threadIdx.x;
    int b = t & 15, jl = t >> 4;
    int jbase = blockIdx.x * 64;
    float s[9];
    #pragma unroll
    for (int r = 0; r < 9; ++r) s[r] = 0.f;
    for (int pass = 0; pass < 4; ++pass) {
        int j = jbase + pass * 16 + jl;
        float t0 = tmat[(size_t)(b*3+0) * N_NODES + j];
        float t1 = tmat[(size_t)(b*3+1) * N_NODES + j];
        float t2 = tmat[(size_t)(b*3+2) * N_NODES + j];
        const float* cp = c + (size_t)j * 48 + b * 3;
        float c0 = cp[0], c1 = cp[1], c2 = cp[2];
        s[0] += t0*c0; s[1] += t0*c1; s[2] += t0*c2;
        s[3] += t1*c0; s[4] += t1*c1; s[5] += t1*c2;
        s[6] += t2*c0; s[7] += t2*c1; s[8] += t2*c2;
    }
    #pragma unroll
    for (int r = 0; r < 9; ++r) shred[t * 9 + r] = s[r];
    __syncthreads();
    if (t < 144) {
        int bb = t / 9, r = t % 9;
        float acc = 0.f;
        #pragma unroll
        for (int g = 0; g < 16; ++g)
            acc += shred[(g * 16 + bb) * 9 + r];
        atomicAdd(&out[t], acc);
    }
}

extern "C" void kernel_launch(void* const* d_in, const int* in_sizes, int n_in,
                              void* d_out, int out_size, void* d_ws, size_t ws_size,
                              hipStream_t stream) {
    const float* F     = (const float*)d_in[0];
    const float* pos   = (const float*)d_in[1];
    const int*   esrc  = (const int*)d_in[2];
    const int*   edst  = (const int*)d_in[3];
    const int*   etyp  = (const int*)d_in[4];
    const float* W_in  = (const float*)d_in[5];
    const float* fc1_0 = (const float*)d_in[6];
    const float* fc2_0 = (const float*)d_in[7];
    const float* W_0   = (const float*)d_in[8];
    const float* fc1_1 = (const float*)d_in[9];
    const float* fc2_1 = (const float*)d_in[10];
    const float* W_1   = (const float*)d_in[11];
    const float* W_out = (const float*)d_in[12];
    const float* w2    = (const float*)d_in[13];
    float* out = (float*)d_out;

    float* ws   = (float*)d_ws;
    float* ew   = ws;                     // 6
    float* G    = ws + 16;                // 768
    float* invF = ws + 800;               // 144
    float* bufA = ws + 1024;              // N*256
    float* bufB = bufA + N_NODES*BH;      // N*256
    float* hout = bufB + N_NODES*BH;      // N*48
    float* aArr = hout + N_NODES*48;      // N*48
    float* cArr = aArr + N_NODES*48;      // N*48
    float* tmat = cArr + N_NODES*48;      // N*48
    int* cnt    = (int*)(tmat + N_NODES*48);
    int* off    = cnt + N_NODES;          // N+1
    int* cursor = off + N_NODES + 1;      // N
    int* sedge  = cursor + N_NODES;       // E
    float* partial = (float*)(sedge + N_EDGES);  // NSTRIP * N*48 (25 MB)

    setup_kernel<<<1, 256, 0, stream>>>(F, W_in, fc1_0, fc2_0, fc1_1, fc2_1, ew, G, invF, out, cnt);
    h0_hist_kernel<<<1536, 256, 0, stream>>>(pos, G, bufA, edst, cnt);
    scan_kernel<<<1, 256, 0, stream>>>(cnt, off, cursor);
    fill_kernel<<<512, 256, 0, stream>>>(esrc, edst, etyp, cursor, sedge);
    layer_kernel<<<2048, 256, 0, stream>>>(bufA, bufB, off, sedge, ew,     W_0);
    layer_kernel<<<2048, 256, 0, stream>>>(bufB, bufA, off, sedge, ew + 3, W_1);
    hout_kernel<<<256, 256, 0, stream>>>(bufA, W_out, hout);
    ac_kernel<<<256, 256, 0, stream>>>(hout, esrc, edst, invF, aArr, cArr);
    tmat_kernel<<<1024, 256, 0, stream>>>(w2, aArr, partial);
    reduce_kernel<<<768, 64, 0, stream>>>(partial, tmat);
    stress2_kernel<<<64, 256, 0, stream>>>(tmat, cArr, out);
}